// Round 18
// baseline (256.099 us; speedup 1.0000x reference)
//
#include <hip/hip_runtime.h>

typedef __attribute__((ext_vector_type(8))) short short8;
typedef __attribute__((ext_vector_type(4))) float f32x4;
typedef __attribute__((ext_vector_type(4))) unsigned short us4;

#define MFMA_BF16(a, b, c) __builtin_amdgcn_mfma_f32_16x16x32_bf16((a), (b), (c), 0, 0, 0)

__device__ __forceinline__ unsigned short f2bf(float f) {
  union { float f; unsigned int u; } x; x.f = f;
  unsigned int r = x.u + 0x7FFFu + ((x.u >> 16) & 1u);
  return (unsigned short)(r >> 16);
}
__device__ __forceinline__ float bf2f(unsigned short b) {
  union { float f; unsigned int u; } x; x.u = ((unsigned int)b) << 16;
  return x.f;
}

typedef __attribute__((address_space(3))) unsigned int lds_uint;
typedef const __attribute__((address_space(1))) unsigned int gbl_uint;

__device__ __forceinline__ void gload_lds16(const void* g, void* l) {
  __builtin_amdgcn_global_load_lds((gbl_uint*)g, (lds_uint*)l, 16, 0, 0);
}

// swizzled LDS read: row stride 128 B, colbyte XOR'd with (row&7)<<4
__device__ __forceinline__ short8 lds_swz_read(const unsigned short* base, int row, int colbyte) {
  return *(const short8*)((const char*)base + row * 128 + (colbyte ^ ((row & 7) << 4)));
}

// ------ fused: weight fp32->bf16 convert (blocks 0..12287) + LN1 (12288..16383) --
__global__ __launch_bounds__(256) void cvt_ln(const float* __restrict__ Wq,
                                              const float* __restrict__ Wk,
                                              const float* __restrict__ Wv,
                                              const float* __restrict__ Wo,
                                              const float* __restrict__ W1,
                                              const float* __restrict__ W2,
                                              unsigned short* __restrict__ Wqkv_b,
                                              unsigned short* __restrict__ Wo_b,
                                              unsigned short* __restrict__ W1_b,
                                              unsigned short* __restrict__ W2_b,
                                              const float* __restrict__ x,
                                              const float* __restrict__ g,
                                              const float* __restrict__ be,
                                              unsigned short* __restrict__ lnout) {
  const int b = blockIdx.x;
  const int t = threadIdx.x;
  __shared__ float red[8];
  if (b < 12288) {
    const float* src;
    unsigned short* dst;
    int off;
    if (b < 1024)      { src = Wq; dst = Wqkv_b;           off = b; }
    else if (b < 2048) { src = Wk; dst = Wqkv_b + 1048576; off = b - 1024; }
    else if (b < 3072) { src = Wv; dst = Wqkv_b + 2097152; off = b - 2048; }
    else if (b < 4096) { src = Wo; dst = Wo_b;             off = b - 3072; }
    else if (b < 8192) { src = W1; dst = W1_b;             off = b - 4096; }
    else               { src = W2; dst = W2_b;             off = b - 8192; }
    const int i = off * 256 + t;
    const float4 v = ((const float4*)src)[i];
    us4 o;
    o.x = f2bf(v.x); o.y = f2bf(v.y); o.z = f2bf(v.z); o.w = f2bf(v.w);
    ((us4*)dst)[i] = o;
    return;
  }
  const int row = b - 12288;
  const float4 v = ((const float4*)(x + (size_t)row * 1024))[t];
  float s = v.x + v.y + v.z + v.w;
  float s2 = v.x * v.x + v.y * v.y + v.z * v.z + v.w * v.w;
#pragma unroll
  for (int d = 1; d < 64; d <<= 1) {
    s += __shfl_xor(s, d);
    s2 += __shfl_xor(s2, d);
  }
  const int wid = t >> 6, lane = t & 63;
  if (lane == 0) { red[wid] = s; red[4 + wid] = s2; }
  __syncthreads();
  s = red[0] + red[1] + red[2] + red[3];
  s2 = red[4] + red[5] + red[6] + red[7];
  const float mu = s * (1.0f / 1024.0f);
  const float var = s2 * (1.0f / 1024.0f) - mu * mu;
  const float rstd = rsqrtf(var + 1e-5f);
  const float4 gv = ((const float4*)g)[t];
  const float4 bv = ((const float4*)be)[t];
  us4 o;
  o.x = f2bf((v.x - mu) * rstd * gv.x + bv.x);
  o.y = f2bf((v.y - mu) * rstd * gv.y + bv.y);
  o.z = f2bf((v.z - mu) * rstd * gv.z + bv.z);
  o.w = f2bf((v.w - mu) * rstd * gv.w + bv.w);
  ((us4*)(lnout + (size_t)row * 1024))[t] = o;
}

// ---------------- layernorm: fp32 in -> bf16 out (1024 cols) ----------------
__global__ __launch_bounds__(256) void ln_kernel(const float* __restrict__ x,
                                                 const float* __restrict__ g,
                                                 const float* __restrict__ be,
                                                 unsigned short* __restrict__ out) {
  const int row = blockIdx.x;
  const int t = threadIdx.x;
  const float4 v = ((const float4*)(x + (size_t)row * 1024))[t];
  float s = v.x + v.y + v.z + v.w;
  float s2 = v.x * v.x + v.y * v.y + v.z * v.z + v.w * v.w;
#pragma unroll
  for (int d = 1; d < 64; d <<= 1) {
    s += __shfl_xor(s, d);
    s2 += __shfl_xor(s2, d);
  }
  __shared__ float red[8];
  const int wid = t >> 6, lane = t & 63;
  if (lane == 0) { red[wid] = s; red[4 + wid] = s2; }
  __syncthreads();
  s = red[0] + red[1] + red[2] + red[3];
  s2 = red[4] + red[5] + red[6] + red[7];
  const float mu = s * (1.0f / 1024.0f);
  const float var = s2 * (1.0f / 1024.0f) - mu * mu;
  const float rstd = rsqrtf(var + 1e-5f);
  const float4 gv = ((const float4*)g)[t];
  const float4 bv = ((const float4*)be)[t];
  us4 o;
  o.x = f2bf((v.x - mu) * rstd * gv.x + bv.x);
  o.y = f2bf((v.y - mu) * rstd * gv.y + bv.y);
  o.z = f2bf((v.z - mu) * rstd * gv.z + bv.z);
  o.w = f2bf((v.w - mu) * rstd * gv.w + bv.w);
  ((us4*)(out + (size_t)row * 1024))[t] = o;
}

// ---------------- FFN2 reduce: out = bf16(p0)+bf16(p1) + x1 + b2 ----------------
__global__ __launch_bounds__(256) void ffn2_reduce(float* __restrict__ out,
                                                   const unsigned short* __restrict__ p0,
                                                   const unsigned short* __restrict__ p1,
                                                   const float* __restrict__ x1,
                                                   const float* __restrict__ b2) {
  const int row = blockIdx.x, t = threadIdx.x;
  const size_t i = (size_t)row * 256 + t;
  const us4 a0 = ((const us4*)p0)[i];
  const us4 a1 = ((const us4*)p1)[i];
  const float4 c = ((const float4*)x1)[i];
  const float4 b = ((const float4*)b2)[t];
  float4 v;
  v.x = bf2f(a0.x) + bf2f(a1.x) + c.x + b.x;
  v.y = bf2f(a0.y) + bf2f(a1.y) + c.y + b.y;
  v.z = bf2f(a0.z) + bf2f(a1.z) + c.z + b.z;
  v.w = bf2f(a0.w) + bf2f(a1.w) + c.w + b.w;
  ((float4*)out)[i] = v;
}

// ---------------- GEMM (4-wave, 128-row tiles): counted-vmcnt + T2 swizzle ------
// EPI 0: fused-QKV store (q,k head-permuted bf16; v stored TRANSPOSED [b,h,d,s]
// with sigma(x)=(x&15)*4+(x>>4) k-permutation per 64-block, matching attn's P).
// EPI 1: relu bf16; EPI 2: +res fp32.
template <int BN, int EPI, int MINW = 2>
__global__ __launch_bounds__(256, MINW) void gemm_bf16(const unsigned short* __restrict__ A,
                                                       const unsigned short* __restrict__ B,
                                                       const float* __restrict__ bias,
                                                       const float* __restrict__ biasK,
                                                       const float* __restrict__ biasV,
                                                       const float* __restrict__ res,
                                                       void* __restrict__ outp,
                                                       int M, int N, int K,
                                                       int gx, int gy, int kspl) {
  constexpr int WN = (BN == 128) ? 2 : 1;
  constexpr int WROWS = 128 / (4 / WN);
  constexpr int MW = WROWS / 16;
  constexpr int NW = (BN / WN) / 16;
  constexpr int BCH = BN / 32;
  constexpr int LOADS = 4 + BCH;

  __shared__ __align__(16) unsigned short As[2][128 * 64];
  __shared__ __align__(16) unsigned short Bs[2][BN * 64];

  const int nwg = gridDim.x;
  const int id2 = ((int)blockIdx.x & 7) * (nwg >> 3) + ((int)blockIdx.x >> 3);
  const int bx = id2 % gx;
  const int byz = id2 / gx;
  const int by = byz % gy;
  const int bz = byz / gy;

  const int wid = threadIdx.x >> 6;
  const int lane = threadIdx.x & 63;
  const int lr = lane & 15, lg = lane >> 4;
  const int row0 = by * 128;
  const int col0 = bx * BN;
  const int k0 = bz * kspl;
  const int wm = (wid / WN) * WROWS;
  const int wn = (wid % WN) * (BN / WN);

  const int scol = ((lane & 7) ^ ((lane >> 3) & 7)) * 8;

  auto stage = [&](int buf, int kt) {
#pragma unroll
    for (int i = 0; i < 4; ++i) {
      const int r = wid * 32 + i * 8;
      gload_lds16(A + (size_t)(row0 + r + (lane >> 3)) * K + kt + scol,
                  (void*)&As[buf][r * 64]);
    }
#pragma unroll
    for (int i = 0; i < BCH; ++i) {
      const int r = wid * (8 * BCH) + i * 8;
      gload_lds16(B + (size_t)(col0 + r + (lane >> 3)) * K + kt + scol,
                  (void*)&Bs[buf][r * 64]);
    }
  };

  f32x4 acc[MW][NW];
#pragma unroll
  for (int m = 0; m < MW; ++m)
#pragma unroll
    for (int n = 0; n < NW; ++n) acc[m][n] = (f32x4){0.f, 0.f, 0.f, 0.f};

  auto mma = [&](int buf) {
#pragma unroll
    for (int kk = 0; kk < 64; kk += 32) {
      const int colbyte = kk * 2 + lg * 16;
      short8 av[MW], bv[NW];
#pragma unroll
      for (int m = 0; m < MW; ++m)
        av[m] = lds_swz_read(&As[buf][0], wm + m * 16 + lr, colbyte);
#pragma unroll
      for (int n = 0; n < NW; ++n)
        bv[n] = lds_swz_read(&Bs[buf][0], wn + n * 16 + lr, colbyte);
#pragma unroll
      for (int m = 0; m < MW; ++m)
#pragma unroll
        for (int n = 0; n < NW; ++n) acc[m][n] = MFMA_BF16(av[m], bv[n], acc[m][n]);
    }
  };

  stage(0, k0);
  stage(1, k0 + 64);
  const int ktend = k0 + kspl;
  int cur = 0;
  for (int kt = k0; kt < ktend - 64; kt += 64) {
    asm volatile("s_waitcnt vmcnt(%0)" ::"i"(LOADS) : "memory");
    __builtin_amdgcn_s_barrier();
    __builtin_amdgcn_sched_barrier(0);
    mma(cur);
    __builtin_amdgcn_s_barrier();
    if (kt + 128 < ktend) stage(cur, kt + 128);
    cur ^= 1;
  }
  asm volatile("s_waitcnt vmcnt(0)" ::: "memory");
  __builtin_amdgcn_s_barrier();
  __builtin_amdgcn_sched_barrier(0);
  mma(cur);

#pragma unroll
  for (int m = 0; m < MW; ++m) {
#pragma unroll
    for (int n = 0; n < NW; ++n) {
#pragma unroll
      for (int r = 0; r < 4; ++r) {
        const int row = row0 + wm + m * 16 + lg * 4 + r;
        const int col = col0 + wn + n * 16 + lr;
        if constexpr (EPI == 0) {
          const int which = col >> 10, c = col & 1023;
          const float* bp = (which == 0) ? bias : (which == 1) ? biasK : biasV;
          const float v = acc[m][n][r] + bp[c];
          const unsigned short b16 = f2bf(v);
          const int bb = row >> 11, sl = row & 2047;
          if (which < 2) {
            const size_t idx = (size_t)which * 4194304 +
                (((size_t)bb * 16 + (c >> 6)) * 2048 + sl) * 64 + (c & 63);
            ((unsigned short*)outp)[idx] = b16;
          } else {
            // V^T with sigma permutation inside each 64-key block
            const int sig = ((sl & 15) << 2) | ((sl >> 4) & 3);
            const size_t idx = (size_t)2 * 4194304 +
                (((size_t)bb * 16 + (c >> 6)) * 64 + (c & 63)) * 2048 + (sl & ~63) + sig;
            ((unsigned short*)outp)[idx] = b16;
          }
        } else if constexpr (EPI == 1) {
          const float v = acc[m][n][r] + bias[col];
          ((unsigned short*)outp)[(size_t)row * N + col] = f2bf(fmaxf(v, 0.f));
        } else {
          const float v = acc[m][n][r] + bias[col];
          ((float*)outp)[(size_t)row * N + col] = v + res[(size_t)row * N + col];
        }
      }
    }
  }
}

// ---------------- GEMM (8-wave, BMxBN tiles): counted-vmcnt + T2 swizzle --------
// EPI 1: relu + bias, bf16 store. EPI 4: split-K partial, BF16 store (bz==0 ->
// outp, bz==1 -> part).
template <int BM, int BN, int EPI>
__global__ __launch_bounds__(512, 2) void gemm256(const unsigned short* __restrict__ A,
                                                  const unsigned short* __restrict__ B,
                                                  const float* __restrict__ bias,
                                                  void* __restrict__ part,
                                                  void* __restrict__ outp,
                                                  int M, int N, int K,
                                                  int gx, int gy, int kspl) {
  constexpr int MW = BM / 32;
  constexpr int NW = BN / 64;
  constexpr int A_ISS = BM / 64;
  constexpr int B_ISS = BN / 64;
  constexpr int LOADS = A_ISS + B_ISS;

  __shared__ __align__(16) unsigned short As[2][BM * 64];
  __shared__ __align__(16) unsigned short Bs[2][BN * 64];

  const int nwg = gridDim.x;
  const int id2 = ((int)blockIdx.x & 7) * (nwg >> 3) + ((int)blockIdx.x >> 3);
  const int bx = id2 % gx;
  const int byz = id2 / gx;
  const int by = byz % gy;
  const int bz = byz / gy;

  const int wid = threadIdx.x >> 6;
  const int lane = threadIdx.x & 63;
  const int lr = lane & 15, lg = lane >> 4;
  const int wr = wid >> 2, wc = wid & 3;
  const int row0 = by * BM;
  const int col0 = bx * BN;
  const int k0 = bz * kspl;
  const int wm = wr * (BM / 2);
  const int wn = wc * (BN / 4);

  const int scol = ((lane & 7) ^ ((lane >> 3) & 7)) * 8;

  auto stage = [&](int buf, int kt) {
#pragma unroll
    for (int i = 0; i < A_ISS; ++i) {
      const int r = wid * 8 + i * 64;
      gload_lds16(A + (size_t)(row0 + r + (lane >> 3)) * K + kt + scol,
                  (void*)&As[buf][r * 64]);
    }
#pragma unroll
    for (int i = 0; i < B_ISS; ++i) {
      const int r = wid * 8 + i * 64;
      gload_lds16(B + (size_t)(col0 + r + (lane >> 3)) * K + kt + scol,
                  (void*)&Bs[buf][r * 64]);
    }
  };

  f32x4 acc[MW][NW];
#pragma unroll
  for (int m = 0; m < MW; ++m)
#pragma unroll
    for (int n = 0; n < NW; ++n) acc[m][n] = (f32x4){0.f, 0.f, 0.f, 0.f};

  auto mma = [&](int buf) {
#pragma unroll
    for (int kk = 0; kk < 64; kk += 32) {
      const int colbyte = kk * 2 + lg * 16;
      short8 av[MW], bv[NW];
#pragma unroll
      for (int m = 0; m < MW; ++m)
        av[m] = lds_swz_read(&As[buf][0], wm + m * 16 + lr, colbyte);
#pragma unroll
      for (int n = 0; n < NW; ++n)
        bv[n] = lds_swz_read(&Bs[buf][0], wn + n * 16 + lr, colbyte);
#pragma unroll
      for (int m = 0; m < MW; ++m)
#pragma unroll
        for (int n = 0; n < NW; ++n) acc[m][n] = MFMA_BF16(av[m], bv[n], acc[m][n]);
    }
  };

  stage(0, k0);
  stage(1, k0 + 64);
  const int ktend = k0 + kspl;
  int cur = 0;
  for (int kt = k0; kt < ktend - 64; kt += 64) {
    asm volatile("s_waitcnt vmcnt(%0)" ::"i"(LOADS) : "memory");
    __builtin_amdgcn_s_barrier();
    __builtin_amdgcn_sched_barrier(0);
    mma(cur);
    __builtin_amdgcn_s_barrier();
    if (kt + 128 < ktend) stage(cur, kt + 128);
    cur ^= 1;
  }
  asm volatile("s_waitcnt vmcnt(0)" ::: "memory");
  __builtin_amdgcn_s_barrier();
  __builtin_amdgcn_sched_barrier(0);
  mma(cur);

#pragma unroll
  for (int m = 0; m < MW; ++m) {
#pragma unroll
    for (int n = 0; n < NW; ++n) {
#pragma unroll
      for (int r = 0; r < 4; ++r) {
        const int row = row0 + wm + m * 16 + lg * 4 + r;
        const int col = col0 + wn + n * 16 + lr;
        if constexpr (EPI == 1) {
          const float v = acc[m][n][r] + bias[col];
          ((unsigned short*)outp)[(size_t)row * N + col] = f2bf(fmaxf(v, 0.f));
        } else {
          unsigned short* dst = (unsigned short*)(bz ? part : outp);
          dst[(size_t)row * N + col] = f2bf(acc[m][n][r]);
        }
      }
    }
  }
}

// ---------------- flash attention v4: V^T staged via global_load_lds ------------
// q,k [B,H,S,64] bf16; vt = V^T [B,H,64,S] bf16 (sigma k-permutation per
// 64-block, from QKV epilogue). QBLK=128, MW=2. Per tile: cooperative async Vt
// staging (2 gload issues/wave, chunk-preswizzled source, linear LDS dest);
// K frags register-double-buffered; per-wave P LDS (sigma cols);
// vmcnt(8) retires exactly the Vt gloads (K prefetch stays in flight) before
// the barrier; next tile's gloads issue after the barrier.
__global__ __launch_bounds__(256, 2) void attn_kernel(const unsigned short* __restrict__ q,
                                                      const unsigned short* __restrict__ k,
                                                      const unsigned short* __restrict__ vt,
                                                      unsigned short* __restrict__ o) {
  const int bh = blockIdx.x;
  const int q0 = blockIdx.y * 128;
  const unsigned short* qh = q + (size_t)bh * 2048 * 64;
  const unsigned short* kh = k + (size_t)bh * 2048 * 64;
  const unsigned short* vh = vt + (size_t)bh * 64 * 2048;  // [d][s]
  const int wid = threadIdx.x >> 6, lane = threadIdx.x & 63;
  const int lr = lane & 15, lg = lane >> 4;
  const int qw = q0 + wid * 32;

  __shared__ __align__(16) unsigned short Vt[2][64 * 64];   // V^T tiles (64 d-rows x 64 k)
  __shared__ __align__(16) unsigned short Ps[4][32 * 64];   // per-wave P, sigma cols

  constexpr float CS = 0.125f * 1.4426950408889634f;
  short8 qf[2][2];
#pragma unroll
  for (int m = 0; m < 2; ++m)
#pragma unroll
    for (int kk = 0; kk < 2; ++kk) {
      short8 t = *(const short8*)&qh[(size_t)(qw + m * 16 + lr) * 64 + kk * 32 + lg * 8];
#pragma unroll
      for (int j = 0; j < 8; ++j) t[j] = (short)f2bf(bf2f((unsigned short)t[j]) * CS);
      qf[m][kk] = t;
    }

  f32x4 po[2][4];
  float lrun[2][4];
#pragma unroll
  for (int m = 0; m < 2; ++m) {
#pragma unroll
    for (int n = 0; n < 4; ++n) po[m][n] = (f32x4){0.f, 0.f, 0.f, 0.f};
#pragma unroll
    for (int r = 0; r < 4; ++r) lrun[m][r] = 0.f;
  }

  const int scol = ((lane & 7) ^ ((lane >> 3) & 7)) * 8;  // chunk pre-swizzle
  char* const PsB = (char*)&Ps[wid][0];

  short8 kfA[4][2], kfB[4][2];

#define LOAD_K(KF, kt)                                                                   \
  {                                                                                      \
    _Pragma("unroll") for (int n = 0; n < 4; ++n) _Pragma("unroll") for (int kk = 0;     \
                                                                         kk < 2; ++kk)  \
        KF[n][kk] =                                                                      \
        *(const short8*)&kh[(size_t)((kt) + n * 16 + lr) * 64 + kk * 32 + lg * 8];       \
  }
// cooperative async V^T tile staging: wave wid stages rows (wid*2+i)*8..+7
#define STAGE_VT(BUF, kt)                                                                \
  {                                                                                      \
    _Pragma("unroll") for (int i = 0; i < 2; ++i) {                                      \
      const int r = (wid * 2 + i) * 8;                                                   \
      gload_lds16(vh + (size_t)(r + (lane >> 3)) * 2048 + (kt) + scol,                   \
                  (void*)&Vt[BUF][r * 64]);                                              \
    }                                                                                    \
  }

  LOAD_K(kfA, 0)
  STAGE_VT(0, 0)

#define STEP(KC, KN, BUF, t)                                                             \
  {                                                                                      \
    f32x4 sc[2][4];                                                                      \
    _Pragma("unroll") for (int m = 0; m < 2; ++m) _Pragma("unroll") for (int n = 0;      \
                                                                         n < 4; ++n)    \
        sc[m][n] = (f32x4){0.f, 0.f, 0.f, 0.f};                                          \
    __builtin_amdgcn_s_setprio(1);                                                       \
    _Pragma("unroll") for (int kk = 0; kk < 2; ++kk)                                     \
        _Pragma("unroll") for (int m = 0; m < 2; ++m)                                    \
        _Pragma("unroll") for (int n = 0; n < 4; ++n)                                    \
        sc[m][n] = MFMA_BF16(qf[m][kk], KC[n][kk], sc[m][n]);                            \
    __builtin_amdgcn_s_setprio(0);                                                       \
    const int ktn = ((t) + 1 < 32) ? ((t) + 1) * 64 : 0;                                 \
    LOAD_K(KN, ktn)                                                                      \
    _Pragma("unroll") for (int m = 0; m < 2; ++m)                                        \
        _Pragma("unroll") for (int r = 0; r < 4; ++r) {                                  \
      const float p0 = __builtin_amdgcn_exp2f(sc[m][0][r]);                              \
      const float p1 = __builtin_amdgcn_exp2f(sc[m][1][r]);                              \
      const float p2 = __builtin_amdgcn_exp2f(sc[m][2][r]);                              \
      const float p3 = __builtin_amdgcn_exp2f(sc[m][3][r]);                              \
      lrun[m][r] += (p0 + p1) + (p2 + p3);                                               \
      unsigned int u0, u1;                                                               \
      asm("v_cvt_pk_bf16_f32 %0, %1, %2" : "=v"(u0) : "v"(p0), "v"(p1));                 \
      asm("v_cvt_pk_bf16_f32 %0, %1, %2" : "=v"(u1) : "v"(p2), "v"(p3));                 \
      const int row = m * 16 + lg * 4 + r;                                               \
      uint2 pk2; pk2.x = u0; pk2.y = u1;                                                 \
      *(uint2*)(PsB + row * 128 + ((lr * 8) ^ ((row & 7) << 4))) = pk2;                  \
    }                                                                                    \
    /* retire this tile's Vt gloads (oldest 2; K prefetch stays) + P stores */           \
    asm volatile("s_waitcnt vmcnt(8) lgkmcnt(0)" ::: "memory");                          \
    __builtin_amdgcn_s_barrier();                                                        \
    __builtin_amdgcn_sched_barrier(0);                                                   \
    STAGE_VT(BUF ^ 1, ktn)  /* safe: all PV(t-1) reads of buf^1 done (barrier) */        \
    __builtin_amdgcn_sched_barrier(0);                                                   \
    _Pragma("unroll") for (int kk = 0; kk < 2; ++kk) {                                   \
      const int coff = kk * 64 + lg * 16;                                                \
      short8 pa[2], vbr[4];                                                              \
      _Pragma("unroll") for (int m = 0; m < 2; ++m) {                                    \
        const int prow = m * 16 + lr;                                                    \
        pa[m] = *(const short8*)(PsB + prow * 128 + (coff ^ ((prow & 7) << 4)));         \
      }                                                                                  \
      _Pragma("unroll") for (int n = 0; n < 4; ++n)                                      \
        vbr[n] = lds_swz_read(&Vt[BUF][0], n * 16 + lr, coff);                           \
      __builtin_amdgcn_s_setprio(1);                                                     \
      _Pragma("unroll") for (int m = 0; m < 2; ++m)                                      \
          _Pragma("unroll") for (int n = 0; n < 4; ++n)                                  \
          po[m][n] = MFMA_BF16(pa[m], vbr[n], po[m][n]);                                 \
      __builtin_amdgcn_s_setprio(0);                                                     \
    }                                                                                    \
  }

  for (int t = 0; t < 32; t += 2) {
    STEP(kfA, kfB, 0, t)
    STEP(kfB, kfA, 1, t + 1)
  }
#undef STEP
#undef LOAD_K
#undef STAGE_VT

#pragma unroll
  for (int d = 1; d < 16; d <<= 1)
#pragma unroll
    for (int m = 0; m < 2; ++m)
#pragma unroll
      for (int r = 0; r < 4; ++r) lrun[m][r] += __shfl_xor(lrun[m][r], d);

  const int b = bh >> 4, hh = bh & 15;
#pragma unroll
  for (int m = 0; m < 2; ++m)
#pragma unroll
    for (int n = 0; n < 4; ++n)
#pragma unroll
      for (int r = 0; r < 4; ++r) {
        const int qrow = qw + m * 16 + lg * 4 + r;
        const int d = n * 16 + lr;
        o[((size_t)b * 2048 + qrow) * 1024 + hh * 64 + d] =
            f2bf(po[m][n][r] / lrun[m][r]);
      }
}

// ---------------- launcher ----------------
extern "C" void kernel_launch(void* const* d_in, const int* in_sizes, int n_in,
                              void* d_out, int out_size, void* d_ws, size_t ws_size,
                              hipStream_t stream) {
  const float* x  = (const float*)d_in[0];
  const float* Wq = (const float*)d_in[1];
  const float* bq = (const float*)d_in[2];
  const float* Wk = (const float*)d_in[3];
  const float* bk = (const float*)d_in[4];
  const float* Wv = (const float*)d_in[5];
  const float* bv = (const float*)d_in[6];
  const float* Wo = (const float*)d_in[7];
  const float* bo = (const float*)d_in[8];
  const float* W1 = (const float*)d_in[9];
  const float* b1 = (const float*)d_in[10];
  const float* W2 = (const float*)d_in[11];
  const float* b2 = (const float*)d_in[12];
  const float* g1 = (const float*)d_in[13];
  const float* be1 = (const float*)d_in[14];
  const float* g2 = (const float*)d_in[15];
  const float* be2 = (const float*)d_in[16];

  char* ws = (char*)d_ws;
  const size_t MB = 1024 * 1024;
  unsigned short* Wqkv_b = (unsigned short*)(ws + 0 * MB);
  unsigned short* Wo_b   = (unsigned short*)(ws + 6 * MB);
  unsigned short* W1_b   = (unsigned short*)(ws + 8 * MB);
  unsigned short* W2_b   = (unsigned short*)(ws + 16 * MB);
  unsigned short* h_b    = (unsigned short*)(ws + 24 * MB);
  unsigned short* qb     = (unsigned short*)(ws + 32 * MB);  // q|k|v^T contiguous
  unsigned short* ab     = (unsigned short*)(ws + 56 * MB);
  float*          x1     = (float*)(ws + 64 * MB);
  unsigned short* fb     = (unsigned short*)(ws + 32 * MB);  // reuse q/k/v region
  unsigned short* p0     = (unsigned short*)(ws + 0 * MB);   // FFN2 partial 0 (8 MB)
  unsigned short* p1     = (unsigned short*)(ws + 8 * MB);   // FFN2 partial 1 (8 MB)

  // weight conversions + LN1 fused into one launch
  cvt_ln<<<16384, 256, 0, stream>>>(Wq, Wk, Wv, Wo, W1, W2, Wqkv_b, Wo_b, W1_b, W2_b,
                                    x, g1, be1, h_b);

  // fused QKV projection (EPI 0: q,k permuted; v transposed+sigma)
  gemm_bf16<128, 0><<<768, 256, 0, stream>>>(h_b, Wqkv_b, bq, bk, bv, nullptr, qb,
                                             4096, 3072, 1024, 24, 32, 1024);

  // attention: x = head (XCD locality), y = q-block (QBLK=128)
  attn_kernel<<<dim3(32, 16), 256, 0, stream>>>(qb, qb + 4194304, qb + 2 * 4194304, ab);

  // O-proj + residual -> x1 (fp32); BN=64 -> 48KB LDS -> 3 blocks/CU
  gemm_bf16<64, 2, 3><<<512, 256, 0, stream>>>(ab, Wo_b, bo, nullptr, nullptr, x, x1,
                                               4096, 1024, 1024, 16, 32, 1024);

  // LN2
  ln_kernel<<<4096, 256, 0, stream>>>(x1, g2, be2, h_b);

  // FFN1 (relu, bf16), 256^2 tiles, 8 waves
  gemm256<256, 256, 1><<<256, 512, 0, stream>>>(h_b, W1_b, b1, nullptr, fb,
                                                4096, 4096, 1024, 16, 16, 1024);

  // FFN2 split-K=2, bf16 raw partials (slice0 -> p0, slice1 -> p1)
  gemm256<128, 256, 4><<<256, 512, 0, stream>>>(fb, W2_b, nullptr, p1, p0,
                                                4096, 1024, 4096, 4, 32, 2048);

  // final reduce: d_out = p0 + p1 + x1 + b2
  ffn2_reduce<<<4096, 256, 0, stream>>>((float*)d_out, p0, p1, x1, b2);
}

// Round 19
// 234.685 us; speedup vs baseline: 1.0912x; 1.0912x over previous
//
#include <hip/hip_runtime.h>

typedef __attribute__((ext_vector_type(8))) short short8;
typedef __attribute__((ext_vector_type(4))) float f32x4;
typedef __attribute__((ext_vector_type(4))) unsigned short us4;

#define MFMA_BF16(a, b, c) __builtin_amdgcn_mfma_f32_16x16x32_bf16((a), (b), (c), 0, 0, 0)

__device__ __forceinline__ unsigned short f2bf(float f) {
  union { float f; unsigned int u; } x; x.f = f;
  unsigned int r = x.u + 0x7FFFu + ((x.u >> 16) & 1u);
  return (unsigned short)(r >> 16);
}
__device__ __forceinline__ float bf2f(unsigned short b) {
  union { float f; unsigned int u; } x; x.u = ((unsigned int)b) << 16;
  return x.f;
}

typedef __attribute__((address_space(3))) unsigned int lds_uint;
typedef const __attribute__((address_space(1))) unsigned int gbl_uint;

__device__ __forceinline__ void gload_lds16(const void* g, void* l) {
  __builtin_amdgcn_global_load_lds((gbl_uint*)g, (lds_uint*)l, 16, 0, 0);
}

// swizzled LDS read: row stride 128 B, colbyte XOR'd with (row&7)<<4
__device__ __forceinline__ short8 lds_swz_read(const unsigned short* base, int row, int colbyte) {
  return *(const short8*)((const char*)base + row * 128 + (colbyte ^ ((row & 7) << 4)));
}

// ------ fused: weight fp32->bf16 convert (blocks 0..12287) + LN1 (12288..16383) --
__global__ __launch_bounds__(256) void cvt_ln(const float* __restrict__ Wq,
                                              const float* __restrict__ Wk,
                                              const float* __restrict__ Wv,
                                              const float* __restrict__ Wo,
                                              const float* __restrict__ W1,
                                              const float* __restrict__ W2,
                                              unsigned short* __restrict__ Wqkv_b,
                                              unsigned short* __restrict__ Wo_b,
                                              unsigned short* __restrict__ W1_b,
                                              unsigned short* __restrict__ W2_b,
                                              const float* __restrict__ x,
                                              const float* __restrict__ g,
                                              const float* __restrict__ be,
                                              unsigned short* __restrict__ lnout) {
  const int b = blockIdx.x;
  const int t = threadIdx.x;
  __shared__ float red[8];
  if (b < 12288) {
    const float* src;
    unsigned short* dst;
    int off;
    if (b < 1024)      { src = Wq; dst = Wqkv_b;           off = b; }
    else if (b < 2048) { src = Wk; dst = Wqkv_b + 1048576; off = b - 1024; }
    else if (b < 3072) { src = Wv; dst = Wqkv_b + 2097152; off = b - 2048; }
    else if (b < 4096) { src = Wo; dst = Wo_b;             off = b - 3072; }
    else if (b < 8192) { src = W1; dst = W1_b;             off = b - 4096; }
    else               { src = W2; dst = W2_b;             off = b - 8192; }
    const int i = off * 256 + t;
    const float4 v = ((const float4*)src)[i];
    us4 o;
    o.x = f2bf(v.x); o.y = f2bf(v.y); o.z = f2bf(v.z); o.w = f2bf(v.w);
    ((us4*)dst)[i] = o;
    return;
  }
  const int row = b - 12288;
  const float4 v = ((const float4*)(x + (size_t)row * 1024))[t];
  float s = v.x + v.y + v.z + v.w;
  float s2 = v.x * v.x + v.y * v.y + v.z * v.z + v.w * v.w;
#pragma unroll
  for (int d = 1; d < 64; d <<= 1) {
    s += __shfl_xor(s, d);
    s2 += __shfl_xor(s2, d);
  }
  const int wid = t >> 6, lane = t & 63;
  if (lane == 0) { red[wid] = s; red[4 + wid] = s2; }
  __syncthreads();
  s = red[0] + red[1] + red[2] + red[3];
  s2 = red[4] + red[5] + red[6] + red[7];
  const float mu = s * (1.0f / 1024.0f);
  const float var = s2 * (1.0f / 1024.0f) - mu * mu;
  const float rstd = rsqrtf(var + 1e-5f);
  const float4 gv = ((const float4*)g)[t];
  const float4 bv = ((const float4*)be)[t];
  us4 o;
  o.x = f2bf((v.x - mu) * rstd * gv.x + bv.x);
  o.y = f2bf((v.y - mu) * rstd * gv.y + bv.y);
  o.z = f2bf((v.z - mu) * rstd * gv.z + bv.z);
  o.w = f2bf((v.w - mu) * rstd * gv.w + bv.w);
  ((us4*)(lnout + (size_t)row * 1024))[t] = o;
}

// ---------------- layernorm: fp32 in -> bf16 out (1024 cols) ----------------
__global__ __launch_bounds__(256) void ln_kernel(const float* __restrict__ x,
                                                 const float* __restrict__ g,
                                                 const float* __restrict__ be,
                                                 unsigned short* __restrict__ out) {
  const int row = blockIdx.x;
  const int t = threadIdx.x;
  const float4 v = ((const float4*)(x + (size_t)row * 1024))[t];
  float s = v.x + v.y + v.z + v.w;
  float s2 = v.x * v.x + v.y * v.y + v.z * v.z + v.w * v.w;
#pragma unroll
  for (int d = 1; d < 64; d <<= 1) {
    s += __shfl_xor(s, d);
    s2 += __shfl_xor(s2, d);
  }
  __shared__ float red[8];
  const int wid = t >> 6, lane = t & 63;
  if (lane == 0) { red[wid] = s; red[4 + wid] = s2; }
  __syncthreads();
  s = red[0] + red[1] + red[2] + red[3];
  s2 = red[4] + red[5] + red[6] + red[7];
  const float mu = s * (1.0f / 1024.0f);
  const float var = s2 * (1.0f / 1024.0f) - mu * mu;
  const float rstd = rsqrtf(var + 1e-5f);
  const float4 gv = ((const float4*)g)[t];
  const float4 bv = ((const float4*)be)[t];
  us4 o;
  o.x = f2bf((v.x - mu) * rstd * gv.x + bv.x);
  o.y = f2bf((v.y - mu) * rstd * gv.y + bv.y);
  o.z = f2bf((v.z - mu) * rstd * gv.z + bv.z);
  o.w = f2bf((v.w - mu) * rstd * gv.w + bv.w);
  ((us4*)(out + (size_t)row * 1024))[t] = o;
}

// ---------------- FFN2 reduce: out = bf16(p0)+bf16(p1) + x1 + b2 ----------------
__global__ __launch_bounds__(256) void ffn2_reduce(float* __restrict__ out,
                                                   const unsigned short* __restrict__ p0,
                                                   const unsigned short* __restrict__ p1,
                                                   const float* __restrict__ x1,
                                                   const float* __restrict__ b2) {
  const int row = blockIdx.x, t = threadIdx.x;
  const size_t i = (size_t)row * 256 + t;
  const us4 a0 = ((const us4*)p0)[i];
  const us4 a1 = ((const us4*)p1)[i];
  const float4 c = ((const float4*)x1)[i];
  const float4 b = ((const float4*)b2)[t];
  float4 v;
  v.x = bf2f(a0.x) + bf2f(a1.x) + c.x + b.x;
  v.y = bf2f(a0.y) + bf2f(a1.y) + c.y + b.y;
  v.z = bf2f(a0.z) + bf2f(a1.z) + c.z + b.z;
  v.w = bf2f(a0.w) + bf2f(a1.w) + c.w + b.w;
  ((float4*)out)[i] = v;
}

// ---------------- GEMM (4-wave, 128-row tiles): counted-vmcnt + T2 swizzle ------
// EPI 0: fused-QKV store. q,k head-permuted bf16 (coalesced scalar). v: staged
// through reused LDS (sigma row permutation applied at LDS write), then written
// as V^T [b,h,d,s] with 16B contiguous stores (coalesced) — byte-identical
// layout to the scattered store, but ~4x fewer/4x larger transactions.
// EPI 1: relu bf16; EPI 2: +res fp32.
template <int BN, int EPI, int MINW = 2>
__global__ __launch_bounds__(256, MINW) void gemm_bf16(const unsigned short* __restrict__ A,
                                                       const unsigned short* __restrict__ B,
                                                       const float* __restrict__ bias,
                                                       const float* __restrict__ biasK,
                                                       const float* __restrict__ biasV,
                                                       const float* __restrict__ res,
                                                       void* __restrict__ outp,
                                                       int M, int N, int K,
                                                       int gx, int gy, int kspl) {
  constexpr int WN = (BN == 128) ? 2 : 1;
  constexpr int WROWS = 128 / (4 / WN);
  constexpr int MW = WROWS / 16;
  constexpr int NW = (BN / WN) / 16;
  constexpr int BCH = BN / 32;
  constexpr int LOADS = 4 + BCH;

  __shared__ __align__(16) unsigned short SMEM[2 * 128 * 64 + 2 * BN * 64];
  auto As = (unsigned short(*)[128 * 64])SMEM;
  auto Bs = (unsigned short(*)[BN * 64])(SMEM + 2 * 128 * 64);

  const int nwg = gridDim.x;
  const int id2 = ((int)blockIdx.x & 7) * (nwg >> 3) + ((int)blockIdx.x >> 3);
  const int bx = id2 % gx;
  const int byz = id2 / gx;
  const int by = byz % gy;
  const int bz = byz / gy;

  const int wid = threadIdx.x >> 6;
  const int lane = threadIdx.x & 63;
  const int lr = lane & 15, lg = lane >> 4;
  const int row0 = by * 128;
  const int col0 = bx * BN;
  const int k0 = bz * kspl;
  const int wm = (wid / WN) * WROWS;
  const int wn = (wid % WN) * (BN / WN);

  const int scol = ((lane & 7) ^ ((lane >> 3) & 7)) * 8;

  auto stage = [&](int buf, int kt) {
#pragma unroll
    for (int i = 0; i < 4; ++i) {
      const int r = wid * 32 + i * 8;
      gload_lds16(A + (size_t)(row0 + r + (lane >> 3)) * K + kt + scol,
                  (void*)&As[buf][r * 64]);
    }
#pragma unroll
    for (int i = 0; i < BCH; ++i) {
      const int r = wid * (8 * BCH) + i * 8;
      gload_lds16(B + (size_t)(col0 + r + (lane >> 3)) * K + kt + scol,
                  (void*)&Bs[buf][r * 64]);
    }
  };

  f32x4 acc[MW][NW];
#pragma unroll
  for (int m = 0; m < MW; ++m)
#pragma unroll
    for (int n = 0; n < NW; ++n) acc[m][n] = (f32x4){0.f, 0.f, 0.f, 0.f};

  auto mma = [&](int buf) {
#pragma unroll
    for (int kk = 0; kk < 64; kk += 32) {
      const int colbyte = kk * 2 + lg * 16;
      short8 av[MW], bv[NW];
#pragma unroll
      for (int m = 0; m < MW; ++m)
        av[m] = lds_swz_read(&As[buf][0], wm + m * 16 + lr, colbyte);
#pragma unroll
      for (int n = 0; n < NW; ++n)
        bv[n] = lds_swz_read(&Bs[buf][0], wn + n * 16 + lr, colbyte);
#pragma unroll
      for (int m = 0; m < MW; ++m)
#pragma unroll
        for (int n = 0; n < NW; ++n) acc[m][n] = MFMA_BF16(av[m], bv[n], acc[m][n]);
    }
  };

  stage(0, k0);
  stage(1, k0 + 64);
  const int ktend = k0 + kspl;
  int cur = 0;
  for (int kt = k0; kt < ktend - 64; kt += 64) {
    asm volatile("s_waitcnt vmcnt(%0)" ::"i"(LOADS) : "memory");
    __builtin_amdgcn_s_barrier();
    __builtin_amdgcn_sched_barrier(0);
    mma(cur);
    __builtin_amdgcn_s_barrier();
    if (kt + 128 < ktend) stage(cur, kt + 128);
    cur ^= 1;
  }
  asm volatile("s_waitcnt vmcnt(0)" ::: "memory");
  __builtin_amdgcn_s_barrier();
  __builtin_amdgcn_sched_barrier(0);
  mma(cur);

  if constexpr (EPI == 0) {
    const int which = col0 >> 10;  // uniform per block (col0 multiple of 128)
    if (which < 2) {
#pragma unroll
      for (int m = 0; m < MW; ++m)
#pragma unroll
        for (int n = 0; n < NW; ++n)
#pragma unroll
          for (int r = 0; r < 4; ++r) {
            const int row = row0 + wm + m * 16 + lg * 4 + r;
            const int col = col0 + wn + n * 16 + lr;
            const int c = col & 1023;
            const float* bp = (which == 0) ? bias : biasK;
            const float v = acc[m][n][r] + bp[c];
            const size_t idx = (size_t)which * 4194304 +
                ((((size_t)(row >> 11)) * 16 + (c >> 6)) * 2048 + (row & 2047)) * 64 +
                (c & 63);
            ((unsigned short*)outp)[idx] = f2bf(v);
          }
    } else {
      // V tile: sigma-permuted transpose via reused LDS, then coalesced V^T store
      unsigned short* Vlds = SMEM;  // 128 cols x stride 144 = 18432 shorts <= SMEM
      __syncthreads();              // staging LDS dead; all mma reads complete
#pragma unroll
      for (int m = 0; m < MW; ++m)
#pragma unroll
        for (int n = 0; n < NW; ++n)
#pragma unroll
          for (int r = 0; r < 4; ++r) {
            const int rl = wm + m * 16 + lg * 4 + r;   // local s
            const int xx = rl & 63;
            const int rs = (rl & ~63) | ((xx & 15) << 2) | (xx >> 4);  // sigma'd
            const int coll = wn + n * 16 + lr;          // local d-col
            const float v = acc[m][n][r] + biasV[(col0 & 1023) + coll];
            Vlds[coll * 144 + rs] = f2bf(v);
          }
      __syncthreads();
      const int cl = threadIdx.x >> 1, h = threadIdx.x & 1;
      const int c = (col0 & 1023) + cl;
      const int bb = row0 >> 11;
      unsigned short* vdst = (unsigned short*)outp + (size_t)2 * 4194304 +
          (((size_t)bb * 16 + (c >> 6)) * 64 + (c & 63)) * 2048 + (row0 & 2047) + h * 64;
#pragma unroll
      for (int w = 0; w < 8; ++w)
        *(short8*)(vdst + w * 8) = *(const short8*)&Vlds[cl * 144 + h * 64 + w * 8];
    }
  } else {
#pragma unroll
    for (int m = 0; m < MW; ++m) {
#pragma unroll
      for (int n = 0; n < NW; ++n) {
#pragma unroll
        for (int r = 0; r < 4; ++r) {
          const int row = row0 + wm + m * 16 + lg * 4 + r;
          const int col = col0 + wn + n * 16 + lr;
          if constexpr (EPI == 1) {
            const float v = acc[m][n][r] + bias[col];
            ((unsigned short*)outp)[(size_t)row * N + col] = f2bf(fmaxf(v, 0.f));
          } else {
            const float v = acc[m][n][r] + bias[col];
            ((float*)outp)[(size_t)row * N + col] = v + res[(size_t)row * N + col];
          }
        }
      }
    }
  }
}

// ---------------- GEMM (8-wave, BMxBN tiles): counted-vmcnt + T2 swizzle --------
// EPI 1: relu + bias, bf16 store. EPI 4: split-K partial, BF16 store (bz==0 ->
// outp, bz==1 -> part).
template <int BM, int BN, int EPI>
__global__ __launch_bounds__(512, 2) void gemm256(const unsigned short* __restrict__ A,
                                                  const unsigned short* __restrict__ B,
                                                  const float* __restrict__ bias,
                                                  void* __restrict__ part,
                                                  void* __restrict__ outp,
                                                  int M, int N, int K,
                                                  int gx, int gy, int kspl) {
  constexpr int MW = BM / 32;
  constexpr int NW = BN / 64;
  constexpr int A_ISS = BM / 64;
  constexpr int B_ISS = BN / 64;
  constexpr int LOADS = A_ISS + B_ISS;

  __shared__ __align__(16) unsigned short As[2][BM * 64];
  __shared__ __align__(16) unsigned short Bs[2][BN * 64];

  const int nwg = gridDim.x;
  const int id2 = ((int)blockIdx.x & 7) * (nwg >> 3) + ((int)blockIdx.x >> 3);
  const int bx = id2 % gx;
  const int byz = id2 / gx;
  const int by = byz % gy;
  const int bz = byz / gy;

  const int wid = threadIdx.x >> 6;
  const int lane = threadIdx.x & 63;
  const int lr = lane & 15, lg = lane >> 4;
  const int wr = wid >> 2, wc = wid & 3;
  const int row0 = by * BM;
  const int col0 = bx * BN;
  const int k0 = bz * kspl;
  const int wm = wr * (BM / 2);
  const int wn = wc * (BN / 4);

  const int scol = ((lane & 7) ^ ((lane >> 3) & 7)) * 8;

  auto stage = [&](int buf, int kt) {
#pragma unroll
    for (int i = 0; i < A_ISS; ++i) {
      const int r = wid * 8 + i * 64;
      gload_lds16(A + (size_t)(row0 + r + (lane >> 3)) * K + kt + scol,
                  (void*)&As[buf][r * 64]);
    }
#pragma unroll
    for (int i = 0; i < B_ISS; ++i) {
      const int r = wid * 8 + i * 64;
      gload_lds16(B + (size_t)(col0 + r + (lane >> 3)) * K + kt + scol,
                  (void*)&Bs[buf][r * 64]);
    }
  };

  f32x4 acc[MW][NW];
#pragma unroll
  for (int m = 0; m < MW; ++m)
#pragma unroll
    for (int n = 0; n < NW; ++n) acc[m][n] = (f32x4){0.f, 0.f, 0.f, 0.f};

  auto mma = [&](int buf) {
#pragma unroll
    for (int kk = 0; kk < 64; kk += 32) {
      const int colbyte = kk * 2 + lg * 16;
      short8 av[MW], bv[NW];
#pragma unroll
      for (int m = 0; m < MW; ++m)
        av[m] = lds_swz_read(&As[buf][0], wm + m * 16 + lr, colbyte);
#pragma unroll
      for (int n = 0; n < NW; ++n)
        bv[n] = lds_swz_read(&Bs[buf][0], wn + n * 16 + lr, colbyte);
#pragma unroll
      for (int m = 0; m < MW; ++m)
#pragma unroll
        for (int n = 0; n < NW; ++n) acc[m][n] = MFMA_BF16(av[m], bv[n], acc[m][n]);
    }
  };

  stage(0, k0);
  stage(1, k0 + 64);
  const int ktend = k0 + kspl;
  int cur = 0;
  for (int kt = k0; kt < ktend - 64; kt += 64) {
    asm volatile("s_waitcnt vmcnt(%0)" ::"i"(LOADS) : "memory");
    __builtin_amdgcn_s_barrier();
    __builtin_amdgcn_sched_barrier(0);
    mma(cur);
    __builtin_amdgcn_s_barrier();
    if (kt + 128 < ktend) stage(cur, kt + 128);
    cur ^= 1;
  }
  asm volatile("s_waitcnt vmcnt(0)" ::: "memory");
  __builtin_amdgcn_s_barrier();
  __builtin_amdgcn_sched_barrier(0);
  mma(cur);

#pragma unroll
  for (int m = 0; m < MW; ++m) {
#pragma unroll
    for (int n = 0; n < NW; ++n) {
#pragma unroll
      for (int r = 0; r < 4; ++r) {
        const int row = row0 + wm + m * 16 + lg * 4 + r;
        const int col = col0 + wn + n * 16 + lr;
        if constexpr (EPI == 1) {
          const float v = acc[m][n][r] + bias[col];
          ((unsigned short*)outp)[(size_t)row * N + col] = f2bf(fmaxf(v, 0.f));
        } else {
          unsigned short* dst = (unsigned short*)(bz ? part : outp);
          dst[(size_t)row * N + col] = f2bf(acc[m][n][r]);
        }
      }
    }
  }
}

// ---------------- flash attention v4: V^T staged via global_load_lds ------------
// (unchanged from R18: 82.9 us measured)
__global__ __launch_bounds__(256, 2) void attn_kernel(const unsigned short* __restrict__ q,
                                                      const unsigned short* __restrict__ k,
                                                      const unsigned short* __restrict__ vt,
                                                      unsigned short* __restrict__ o) {
  const int bh = blockIdx.x;
  const int q0 = blockIdx.y * 128;
  const unsigned short* qh = q + (size_t)bh * 2048 * 64;
  const unsigned short* kh = k + (size_t)bh * 2048 * 64;
  const unsigned short* vh = vt + (size_t)bh * 64 * 2048;  // [d][s]
  const int wid = threadIdx.x >> 6, lane = threadIdx.x & 63;
  const int lr = lane & 15, lg = lane >> 4;
  const int qw = q0 + wid * 32;

  __shared__ __align__(16) unsigned short Vt[2][64 * 64];
  __shared__ __align__(16) unsigned short Ps[4][32 * 64];

  constexpr float CS = 0.125f * 1.4426950408889634f;
  short8 qf[2][2];
#pragma unroll
  for (int m = 0; m < 2; ++m)
#pragma unroll
    for (int kk = 0; kk < 2; ++kk) {
      short8 t = *(const short8*)&qh[(size_t)(qw + m * 16 + lr) * 64 + kk * 32 + lg * 8];
#pragma unroll
      for (int j = 0; j < 8; ++j) t[j] = (short)f2bf(bf2f((unsigned short)t[j]) * CS);
      qf[m][kk] = t;
    }

  f32x4 po[2][4];
  float lrun[2][4];
#pragma unroll
  for (int m = 0; m < 2; ++m) {
#pragma unroll
    for (int n = 0; n < 4; ++n) po[m][n] = (f32x4){0.f, 0.f, 0.f, 0.f};
#pragma unroll
    for (int r = 0; r < 4; ++r) lrun[m][r] = 0.f;
  }

  const int scol = ((lane & 7) ^ ((lane >> 3) & 7)) * 8;
  char* const PsB = (char*)&Ps[wid][0];

  short8 kfA[4][2], kfB[4][2];

#define LOAD_K(KF, kt)                                                                   \
  {                                                                                      \
    _Pragma("unroll") for (int n = 0; n < 4; ++n) _Pragma("unroll") for (int kk = 0;     \
                                                                         kk < 2; ++kk)  \
        KF[n][kk] =                                                                      \
        *(const short8*)&kh[(size_t)((kt) + n * 16 + lr) * 64 + kk * 32 + lg * 8];       \
  }
#define STAGE_VT(BUF, kt)                                                                \
  {                                                                                      \
    _Pragma("unroll") for (int i = 0; i < 2; ++i) {                                      \
      const int r = (wid * 2 + i) * 8;                                                   \
      gload_lds16(vh + (size_t)(r + (lane >> 3)) * 2048 + (kt) + scol,                   \
                  (void*)&Vt[BUF][r * 64]);                                              \
    }                                                                                    \
  }

  LOAD_K(kfA, 0)
  STAGE_VT(0, 0)

#define STEP(KC, KN, BUF, t)                                                             \
  {                                                                                      \
    f32x4 sc[2][4];                                                                      \
    _Pragma("unroll") for (int m = 0; m < 2; ++m) _Pragma("unroll") for (int n = 0;      \
                                                                         n < 4; ++n)    \
        sc[m][n] = (f32x4){0.f, 0.f, 0.f, 0.f};                                          \
    __builtin_amdgcn_s_setprio(1);                                                       \
    _Pragma("unroll") for (int kk = 0; kk < 2; ++kk)                                     \
        _Pragma("unroll") for (int m = 0; m < 2; ++m)                                    \
        _Pragma("unroll") for (int n = 0; n < 4; ++n)                                    \
        sc[m][n] = MFMA_BF16(qf[m][kk], KC[n][kk], sc[m][n]);                            \
    __builtin_amdgcn_s_setprio(0);                                                       \
    const int ktn = ((t) + 1 < 32) ? ((t) + 1) * 64 : 0;                                 \
    LOAD_K(KN, ktn)                                                                      \
    _Pragma("unroll") for (int m = 0; m < 2; ++m)                                        \
        _Pragma("unroll") for (int r = 0; r < 4; ++r) {                                  \
      const float p0 = __builtin_amdgcn_exp2f(sc[m][0][r]);                              \
      const float p1 = __builtin_amdgcn_exp2f(sc[m][1][r]);                              \
      const float p2 = __builtin_amdgcn_exp2f(sc[m][2][r]);                              \
      const float p3 = __builtin_amdgcn_exp2f(sc[m][3][r]);                              \
      lrun[m][r] += (p0 + p1) + (p2 + p3);                                               \
      unsigned int u0, u1;                                                               \
      asm("v_cvt_pk_bf16_f32 %0, %1, %2" : "=v"(u0) : "v"(p0), "v"(p1));                 \
      asm("v_cvt_pk_bf16_f32 %0, %1, %2" : "=v"(u1) : "v"(p2), "v"(p3));                 \
      const int row = m * 16 + lg * 4 + r;                                               \
      uint2 pk2; pk2.x = u0; pk2.y = u1;                                                 \
      *(uint2*)(PsB + row * 128 + ((lr * 8) ^ ((row & 7) << 4))) = pk2;                  \
    }                                                                                    \
    asm volatile("s_waitcnt vmcnt(8) lgkmcnt(0)" ::: "memory");                          \
    __builtin_amdgcn_s_barrier();                                                        \
    __builtin_amdgcn_sched_barrier(0);                                                   \
    STAGE_VT(BUF ^ 1, ktn)                                                               \
    __builtin_amdgcn_sched_barrier(0);                                                   \
    _Pragma("unroll") for (int kk = 0; kk < 2; ++kk) {                                   \
      const int coff = kk * 64 + lg * 16;                                                \
      short8 pa[2], vbr[4];                                                              \
      _Pragma("unroll") for (int m = 0; m < 2; ++m) {                                    \
        const int prow = m * 16 + lr;                                                    \
        pa[m] = *(const short8*)(PsB + prow * 128 + (coff ^ ((prow & 7) << 4)));         \
      }                                                                                  \
      _Pragma("unroll") for (int n = 0; n < 4; ++n)                                      \
        vbr[n] = lds_swz_read(&Vt[BUF][0], n * 16 + lr, coff);                           \
      __builtin_amdgcn_s_setprio(1);                                                     \
      _Pragma("unroll") for (int m = 0; m < 2; ++m)                                      \
          _Pragma("unroll") for (int n = 0; n < 4; ++n)                                  \
          po[m][n] = MFMA_BF16(pa[m], vbr[n], po[m][n]);                                 \
      __builtin_amdgcn_s_setprio(0);                                                     \
    }                                                                                    \
  }

  for (int t = 0; t < 32; t += 2) {
    STEP(kfA, kfB, 0, t)
    STEP(kfB, kfA, 1, t + 1)
  }
#undef STEP
#undef LOAD_K
#undef STAGE_VT

#pragma unroll
  for (int d = 1; d < 16; d <<= 1)
#pragma unroll
    for (int m = 0; m < 2; ++m)
#pragma unroll
      for (int r = 0; r < 4; ++r) lrun[m][r] += __shfl_xor(lrun[m][r], d);

  const int b = bh >> 4, hh = bh & 15;
#pragma unroll
  for (int m = 0; m < 2; ++m)
#pragma unroll
    for (int n = 0; n < 4; ++n)
#pragma unroll
      for (int r = 0; r < 4; ++r) {
        const int qrow = qw + m * 16 + lg * 4 + r;
        const int d = n * 16 + lr;
        o[((size_t)b * 2048 + qrow) * 1024 + hh * 64 + d] =
            f2bf(po[m][n][r] / lrun[m][r]);
      }
}

// ---------------- launcher ----------------
extern "C" void kernel_launch(void* const* d_in, const int* in_sizes, int n_in,
                              void* d_out, int out_size, void* d_ws, size_t ws_size,
                              hipStream_t stream) {
  const float* x  = (const float*)d_in[0];
  const float* Wq = (const float*)d_in[1];
  const float* bq = (const float*)d_in[2];
  const float* Wk = (const float*)d_in[3];
  const float* bk = (const float*)d_in[4];
  const float* Wv = (const float*)d_in[5];
  const float* bv = (const float*)d_in[6];
  const float* Wo = (const float*)d_in[7];
  const float* bo = (const float*)d_in[8];
  const float* W1 = (const float*)d_in[9];
  const float* b1 = (const float*)d_in[10];
  const float* W2 = (const float*)d_in[11];
  const float* b2 = (const float*)d_in[12];
  const float* g1 = (const float*)d_in[13];
  const float* be1 = (const float*)d_in[14];
  const float* g2 = (const float*)d_in[15];
  const float* be2 = (const float*)d_in[16];

  char* ws = (char*)d_ws;
  const size_t MB = 1024 * 1024;
  unsigned short* Wqkv_b = (unsigned short*)(ws + 0 * MB);
  unsigned short* Wo_b   = (unsigned short*)(ws + 6 * MB);
  unsigned short* W1_b   = (unsigned short*)(ws + 8 * MB);
  unsigned short* W2_b   = (unsigned short*)(ws + 16 * MB);
  unsigned short* h_b    = (unsigned short*)(ws + 24 * MB);
  unsigned short* qb     = (unsigned short*)(ws + 32 * MB);  // q|k|v^T contiguous
  unsigned short* ab     = (unsigned short*)(ws + 56 * MB);
  float*          x1     = (float*)(ws + 64 * MB);
  unsigned short* fb     = (unsigned short*)(ws + 32 * MB);  // reuse q/k/v region
  unsigned short* p0     = (unsigned short*)(ws + 0 * MB);   // FFN2 partial 0 (8 MB)
  unsigned short* p1     = (unsigned short*)(ws + 8 * MB);   // FFN2 partial 1 (8 MB)

  // weight conversions + LN1 fused into one launch
  cvt_ln<<<16384, 256, 0, stream>>>(Wq, Wk, Wv, Wo, W1, W2, Wqkv_b, Wo_b, W1_b, W2_b,
                                    x, g1, be1, h_b);

  // fused QKV projection (EPI 0: q,k permuted; v transposed+sigma, coalesced)
  gemm_bf16<128, 0><<<768, 256, 0, stream>>>(h_b, Wqkv_b, bq, bk, bv, nullptr, qb,
                                             4096, 3072, 1024, 24, 32, 1024);

  // attention: x = head (XCD locality), y = q-block (QBLK=128)
  attn_kernel<<<dim3(32, 16), 256, 0, stream>>>(qb, qb + 4194304, qb + 2 * 4194304, ab);

  // O-proj + residual -> x1 (fp32); BN=64 -> 48KB LDS -> 3 blocks/CU
  gemm_bf16<64, 2, 3><<<512, 256, 0, stream>>>(ab, Wo_b, bo, nullptr, nullptr, x, x1,
                                               4096, 1024, 1024, 16, 32, 1024);

  // LN2
  ln_kernel<<<4096, 256, 0, stream>>>(x1, g2, be2, h_b);

  // FFN1 (relu, bf16), 256^2 tiles, 8 waves
  gemm256<256, 256, 1><<<256, 512, 0, stream>>>(h_b, W1_b, b1, nullptr, fb,
                                                4096, 4096, 1024, 16, 16, 1024);

  // FFN2 split-K=2, bf16 raw partials (slice0 -> p0, slice1 -> p1)
  gemm256<128, 256, 4><<<256, 512, 0, stream>>>(fb, W2_b, nullptr, p1, p0,
                                                4096, 1024, 4096, 4, 32, 2048);

  // final reduce: d_out = p0 + p1 + x1 + b2
  ffn2_reduce<<<4096, 256, 0, stream>>>((float*)d_out, p0, p1, x1, b2);
}

// Round 20
// 231.658 us; speedup vs baseline: 1.1055x; 1.0131x over previous
//
#include <hip/hip_runtime.h>

typedef __attribute__((ext_vector_type(8))) short short8;
typedef __attribute__((ext_vector_type(4))) float f32x4;
typedef __attribute__((ext_vector_type(4))) unsigned short us4;

#define MFMA_BF16(a, b, c) __builtin_amdgcn_mfma_f32_16x16x32_bf16((a), (b), (c), 0, 0, 0)

__device__ __forceinline__ unsigned short f2bf(float f) {
  union { float f; unsigned int u; } x; x.f = f;
  unsigned int r = x.u + 0x7FFFu + ((x.u >> 16) & 1u);
  return (unsigned short)(r >> 16);
}
__device__ __forceinline__ float bf2f(unsigned short b) {
  union { float f; unsigned int u; } x; x.u = ((unsigned int)b) << 16;
  return x.f;
}

typedef __attribute__((address_space(3))) unsigned int lds_uint;
typedef const __attribute__((address_space(1))) unsigned int gbl_uint;

__device__ __forceinline__ void gload_lds16(const void* g, void* l) {
  __builtin_amdgcn_global_load_lds((gbl_uint*)g, (lds_uint*)l, 16, 0, 0);
}

// swizzled LDS read: row stride 128 B, colbyte XOR'd with (row&7)<<4
__device__ __forceinline__ short8 lds_swz_read(const unsigned short* base, int row, int colbyte) {
  return *(const short8*)((const char*)base + row * 128 + (colbyte ^ ((row & 7) << 4)));
}

// ------ fused: weight fp32->bf16 convert (blocks 0..12287) + LN1 (12288..16383) --
__global__ __launch_bounds__(256) void cvt_ln(const float* __restrict__ Wq,
                                              const float* __restrict__ Wk,
                                              const float* __restrict__ Wv,
                                              const float* __restrict__ Wo,
                                              const float* __restrict__ W1,
                                              const float* __restrict__ W2,
                                              unsigned short* __restrict__ Wqkv_b,
                                              unsigned short* __restrict__ Wo_b,
                                              unsigned short* __restrict__ W1_b,
                                              unsigned short* __restrict__ W2_b,
                                              const float* __restrict__ x,
                                              const float* __restrict__ g,
                                              const float* __restrict__ be,
                                              unsigned short* __restrict__ lnout) {
  const int b = blockIdx.x;
  const int t = threadIdx.x;
  __shared__ float red[8];
  if (b < 12288) {
    const float* src;
    unsigned short* dst;
    int off;
    if (b < 1024)      { src = Wq; dst = Wqkv_b;           off = b; }
    else if (b < 2048) { src = Wk; dst = Wqkv_b + 1048576; off = b - 1024; }
    else if (b < 3072) { src = Wv; dst = Wqkv_b + 2097152; off = b - 2048; }
    else if (b < 4096) { src = Wo; dst = Wo_b;             off = b - 3072; }
    else if (b < 8192) { src = W1; dst = W1_b;             off = b - 4096; }
    else               { src = W2; dst = W2_b;             off = b - 8192; }
    const int i = off * 256 + t;
    const float4 v = ((const float4*)src)[i];
    us4 o;
    o.x = f2bf(v.x); o.y = f2bf(v.y); o.z = f2bf(v.z); o.w = f2bf(v.w);
    ((us4*)dst)[i] = o;
    return;
  }
  const int row = b - 12288;
  const float4 v = ((const float4*)(x + (size_t)row * 1024))[t];
  float s = v.x + v.y + v.z + v.w;
  float s2 = v.x * v.x + v.y * v.y + v.z * v.z + v.w * v.w;
#pragma unroll
  for (int d = 1; d < 64; d <<= 1) {
    s += __shfl_xor(s, d);
    s2 += __shfl_xor(s2, d);
  }
  const int wid = t >> 6, lane = t & 63;
  if (lane == 0) { red[wid] = s; red[4 + wid] = s2; }
  __syncthreads();
  s = red[0] + red[1] + red[2] + red[3];
  s2 = red[4] + red[5] + red[6] + red[7];
  const float mu = s * (1.0f / 1024.0f);
  const float var = s2 * (1.0f / 1024.0f) - mu * mu;
  const float rstd = rsqrtf(var + 1e-5f);
  const float4 gv = ((const float4*)g)[t];
  const float4 bv = ((const float4*)be)[t];
  us4 o;
  o.x = f2bf((v.x - mu) * rstd * gv.x + bv.x);
  o.y = f2bf((v.y - mu) * rstd * gv.y + bv.y);
  o.z = f2bf((v.z - mu) * rstd * gv.z + bv.z);
  o.w = f2bf((v.w - mu) * rstd * gv.w + bv.w);
  ((us4*)(lnout + (size_t)row * 1024))[t] = o;
}

// ---------------- layernorm: fp32 in -> bf16 out (1024 cols) ----------------
__global__ __launch_bounds__(256) void ln_kernel(const float* __restrict__ x,
                                                 const float* __restrict__ g,
                                                 const float* __restrict__ be,
                                                 unsigned short* __restrict__ out) {
  const int row = blockIdx.x;
  const int t = threadIdx.x;
  const float4 v = ((const float4*)(x + (size_t)row * 1024))[t];
  float s = v.x + v.y + v.z + v.w;
  float s2 = v.x * v.x + v.y * v.y + v.z * v.z + v.w * v.w;
#pragma unroll
  for (int d = 1; d < 64; d <<= 1) {
    s += __shfl_xor(s, d);
    s2 += __shfl_xor(s2, d);
  }
  __shared__ float red[8];
  const int wid = t >> 6, lane = t & 63;
  if (lane == 0) { red[wid] = s; red[4 + wid] = s2; }
  __syncthreads();
  s = red[0] + red[1] + red[2] + red[3];
  s2 = red[4] + red[5] + red[6] + red[7];
  const float mu = s * (1.0f / 1024.0f);
  const float var = s2 * (1.0f / 1024.0f) - mu * mu;
  const float rstd = rsqrtf(var + 1e-5f);
  const float4 gv = ((const float4*)g)[t];
  const float4 bv = ((const float4*)be)[t];
  us4 o;
  o.x = f2bf((v.x - mu) * rstd * gv.x + bv.x);
  o.y = f2bf((v.y - mu) * rstd * gv.y + bv.y);
  o.z = f2bf((v.z - mu) * rstd * gv.z + bv.z);
  o.w = f2bf((v.w - mu) * rstd * gv.w + bv.w);
  ((us4*)(out + (size_t)row * 1024))[t] = o;
}

// ---------------- FFN2 reduce: out = bf16(p0)+bf16(p1) + x1 + b2 ----------------
__global__ __launch_bounds__(256) void ffn2_reduce(float* __restrict__ out,
                                                   const unsigned short* __restrict__ p0,
                                                   const unsigned short* __restrict__ p1,
                                                   const float* __restrict__ x1,
                                                   const float* __restrict__ b2) {
  const int row = blockIdx.x, t = threadIdx.x;
  const size_t i = (size_t)row * 256 + t;
  const us4 a0 = ((const us4*)p0)[i];
  const us4 a1 = ((const us4*)p1)[i];
  const float4 c = ((const float4*)x1)[i];
  const float4 b = ((const float4*)b2)[t];
  float4 v;
  v.x = bf2f(a0.x) + bf2f(a1.x) + c.x + b.x;
  v.y = bf2f(a0.y) + bf2f(a1.y) + c.y + b.y;
  v.z = bf2f(a0.z) + bf2f(a1.z) + c.z + b.z;
  v.w = bf2f(a0.w) + bf2f(a1.w) + c.w + b.w;
  ((float4*)out)[i] = v;
}

// ---------------- GEMM (4-wave, 128-row tiles): counted-vmcnt + T2 swizzle ------
template <int BN, int EPI, int MINW = 2>
__global__ __launch_bounds__(256, MINW) void gemm_bf16(const unsigned short* __restrict__ A,
                                                       const unsigned short* __restrict__ B,
                                                       const float* __restrict__ bias,
                                                       const float* __restrict__ biasK,
                                                       const float* __restrict__ biasV,
                                                       const float* __restrict__ res,
                                                       void* __restrict__ outp,
                                                       int M, int N, int K,
                                                       int gx, int gy, int kspl) {
  constexpr int WN = (BN == 128) ? 2 : 1;
  constexpr int WROWS = 128 / (4 / WN);
  constexpr int MW = WROWS / 16;
  constexpr int NW = (BN / WN) / 16;
  constexpr int BCH = BN / 32;
  constexpr int LOADS = 4 + BCH;

  __shared__ __align__(16) unsigned short SMEM[2 * 128 * 64 + 2 * BN * 64];
  auto As = (unsigned short(*)[128 * 64])SMEM;
  auto Bs = (unsigned short(*)[BN * 64])(SMEM + 2 * 128 * 64);

  const int nwg = gridDim.x;
  const int id2 = ((int)blockIdx.x & 7) * (nwg >> 3) + ((int)blockIdx.x >> 3);
  const int bx = id2 % gx;
  const int byz = id2 / gx;
  const int by = byz % gy;
  const int bz = byz / gy;

  const int wid = threadIdx.x >> 6;
  const int lane = threadIdx.x & 63;
  const int lr = lane & 15, lg = lane >> 4;
  const int row0 = by * 128;
  const int col0 = bx * BN;
  const int k0 = bz * kspl;
  const int wm = (wid / WN) * WROWS;
  const int wn = (wid % WN) * (BN / WN);

  const int scol = ((lane & 7) ^ ((lane >> 3) & 7)) * 8;

  auto stage = [&](int buf, int kt) {
#pragma unroll
    for (int i = 0; i < 4; ++i) {
      const int r = wid * 32 + i * 8;
      gload_lds16(A + (size_t)(row0 + r + (lane >> 3)) * K + kt + scol,
                  (void*)&As[buf][r * 64]);
    }
#pragma unroll
    for (int i = 0; i < BCH; ++i) {
      const int r = wid * (8 * BCH) + i * 8;
      gload_lds16(B + (size_t)(col0 + r + (lane >> 3)) * K + kt + scol,
                  (void*)&Bs[buf][r * 64]);
    }
  };

  f32x4 acc[MW][NW];
#pragma unroll
  for (int m = 0; m < MW; ++m)
#pragma unroll
    for (int n = 0; n < NW; ++n) acc[m][n] = (f32x4){0.f, 0.f, 0.f, 0.f};

  auto mma = [&](int buf) {
#pragma unroll
    for (int kk = 0; kk < 64; kk += 32) {
      const int colbyte = kk * 2 + lg * 16;
      short8 av[MW], bv[NW];
#pragma unroll
      for (int m = 0; m < MW; ++m)
        av[m] = lds_swz_read(&As[buf][0], wm + m * 16 + lr, colbyte);
#pragma unroll
      for (int n = 0; n < NW; ++n)
        bv[n] = lds_swz_read(&Bs[buf][0], wn + n * 16 + lr, colbyte);
#pragma unroll
      for (int m = 0; m < MW; ++m)
#pragma unroll
        for (int n = 0; n < NW; ++n) acc[m][n] = MFMA_BF16(av[m], bv[n], acc[m][n]);
    }
  };

  stage(0, k0);
  stage(1, k0 + 64);
  const int ktend = k0 + kspl;
  int cur = 0;
  for (int kt = k0; kt < ktend - 64; kt += 64) {
    asm volatile("s_waitcnt vmcnt(%0)" ::"i"(LOADS) : "memory");
    __builtin_amdgcn_s_barrier();
    __builtin_amdgcn_sched_barrier(0);
    mma(cur);
    __builtin_amdgcn_s_barrier();
    if (kt + 128 < ktend) stage(cur, kt + 128);
    cur ^= 1;
  }
  asm volatile("s_waitcnt vmcnt(0)" ::: "memory");
  __builtin_amdgcn_s_barrier();
  __builtin_amdgcn_sched_barrier(0);
  mma(cur);

  if constexpr (EPI == 0) {
    const int which = col0 >> 10;  // uniform per block (col0 multiple of 128)
    if (which < 2) {
#pragma unroll
      for (int m = 0; m < MW; ++m)
#pragma unroll
        for (int n = 0; n < NW; ++n)
#pragma unroll
          for (int r = 0; r < 4; ++r) {
            const int row = row0 + wm + m * 16 + lg * 4 + r;
            const int col = col0 + wn + n * 16 + lr;
            const int c = col & 1023;
            const float* bp = (which == 0) ? bias : biasK;
            const float v = acc[m][n][r] + bp[c];
            const size_t idx = (size_t)which * 4194304 +
                ((((size_t)(row >> 11)) * 16 + (c >> 6)) * 2048 + (row & 2047)) * 64 +
                (c & 63);
            ((unsigned short*)outp)[idx] = f2bf(v);
          }
    } else {
      // V tile: sigma-permuted transpose via reused LDS, then coalesced V^T store
      unsigned short* Vlds = SMEM;
      __syncthreads();
#pragma unroll
      for (int m = 0; m < MW; ++m)
#pragma unroll
        for (int n = 0; n < NW; ++n)
#pragma unroll
          for (int r = 0; r < 4; ++r) {
            const int rl = wm + m * 16 + lg * 4 + r;
            const int xx = rl & 63;
            const int rs = (rl & ~63) | ((xx & 15) << 2) | (xx >> 4);
            const int coll = wn + n * 16 + lr;
            const float v = acc[m][n][r] + biasV[(col0 & 1023) + coll];
            Vlds[coll * 144 + rs] = f2bf(v);
          }
      __syncthreads();
      const int cl = threadIdx.x >> 1, h = threadIdx.x & 1;
      const int c = (col0 & 1023) + cl;
      const int bb = row0 >> 11;
      unsigned short* vdst = (unsigned short*)outp + (size_t)2 * 4194304 +
          (((size_t)bb * 16 + (c >> 6)) * 64 + (c & 63)) * 2048 + (row0 & 2047) + h * 64;
#pragma unroll
      for (int w = 0; w < 8; ++w)
        *(short8*)(vdst + w * 8) = *(const short8*)&Vlds[cl * 144 + h * 64 + w * 8];
    }
  } else {
#pragma unroll
    for (int m = 0; m < MW; ++m) {
#pragma unroll
      for (int n = 0; n < NW; ++n) {
#pragma unroll
        for (int r = 0; r < 4; ++r) {
          const int row = row0 + wm + m * 16 + lg * 4 + r;
          const int col = col0 + wn + n * 16 + lr;
          if constexpr (EPI == 1) {
            const float v = acc[m][n][r] + bias[col];
            ((unsigned short*)outp)[(size_t)row * N + col] = f2bf(fmaxf(v, 0.f));
          } else {
            const float v = acc[m][n][r] + bias[col];
            ((float*)outp)[(size_t)row * N + col] = v + res[(size_t)row * N + col];
          }
        }
      }
    }
  }
}

// ---------------- GEMM (8-wave, BMxBN tiles): counted-vmcnt + T2 swizzle --------
template <int BM, int BN, int EPI>
__global__ __launch_bounds__(512, 2) void gemm256(const unsigned short* __restrict__ A,
                                                  const unsigned short* __restrict__ B,
                                                  const float* __restrict__ bias,
                                                  void* __restrict__ part,
                                                  void* __restrict__ outp,
                                                  int M, int N, int K,
                                                  int gx, int gy, int kspl) {
  constexpr int MW = BM / 32;
  constexpr int NW = BN / 64;
  constexpr int A_ISS = BM / 64;
  constexpr int B_ISS = BN / 64;
  constexpr int LOADS = A_ISS + B_ISS;

  __shared__ __align__(16) unsigned short As[2][BM * 64];
  __shared__ __align__(16) unsigned short Bs[2][BN * 64];

  const int nwg = gridDim.x;
  const int id2 = ((int)blockIdx.x & 7) * (nwg >> 3) + ((int)blockIdx.x >> 3);
  const int bx = id2 % gx;
  const int byz = id2 / gx;
  const int by = byz % gy;
  const int bz = byz / gy;

  const int wid = threadIdx.x >> 6;
  const int lane = threadIdx.x & 63;
  const int lr = lane & 15, lg = lane >> 4;
  const int wr = wid >> 2, wc = wid & 3;
  const int row0 = by * BM;
  const int col0 = bx * BN;
  const int k0 = bz * kspl;
  const int wm = wr * (BM / 2);
  const int wn = wc * (BN / 4);

  const int scol = ((lane & 7) ^ ((lane >> 3) & 7)) * 8;

  auto stage = [&](int buf, int kt) {
#pragma unroll
    for (int i = 0; i < A_ISS; ++i) {
      const int r = wid * 8 + i * 64;
      gload_lds16(A + (size_t)(row0 + r + (lane >> 3)) * K + kt + scol,
                  (void*)&As[buf][r * 64]);
    }
#pragma unroll
    for (int i = 0; i < B_ISS; ++i) {
      const int r = wid * 8 + i * 64;
      gload_lds16(B + (size_t)(col0 + r + (lane >> 3)) * K + kt + scol,
                  (void*)&Bs[buf][r * 64]);
    }
  };

  f32x4 acc[MW][NW];
#pragma unroll
  for (int m = 0; m < MW; ++m)
#pragma unroll
    for (int n = 0; n < NW; ++n) acc[m][n] = (f32x4){0.f, 0.f, 0.f, 0.f};

  auto mma = [&](int buf) {
#pragma unroll
    for (int kk = 0; kk < 64; kk += 32) {
      const int colbyte = kk * 2 + lg * 16;
      short8 av[MW], bv[NW];
#pragma unroll
      for (int m = 0; m < MW; ++m)
        av[m] = lds_swz_read(&As[buf][0], wm + m * 16 + lr, colbyte);
#pragma unroll
      for (int n = 0; n < NW; ++n)
        bv[n] = lds_swz_read(&Bs[buf][0], wn + n * 16 + lr, colbyte);
#pragma unroll
      for (int m = 0; m < MW; ++m)
#pragma unroll
        for (int n = 0; n < NW; ++n) acc[m][n] = MFMA_BF16(av[m], bv[n], acc[m][n]);
    }
  };

  stage(0, k0);
  stage(1, k0 + 64);
  const int ktend = k0 + kspl;
  int cur = 0;
  for (int kt = k0; kt < ktend - 64; kt += 64) {
    asm volatile("s_waitcnt vmcnt(%0)" ::"i"(LOADS) : "memory");
    __builtin_amdgcn_s_barrier();
    __builtin_amdgcn_sched_barrier(0);
    mma(cur);
    __builtin_amdgcn_s_barrier();
    if (kt + 128 < ktend) stage(cur, kt + 128);
    cur ^= 1;
  }
  asm volatile("s_waitcnt vmcnt(0)" ::: "memory");
  __builtin_amdgcn_s_barrier();
  __builtin_amdgcn_sched_barrier(0);
  mma(cur);

#pragma unroll
  for (int m = 0; m < MW; ++m) {
#pragma unroll
    for (int n = 0; n < NW; ++n) {
#pragma unroll
      for (int r = 0; r < 4; ++r) {
        const int row = row0 + wm + m * 16 + lg * 4 + r;
        const int col = col0 + wn + n * 16 + lr;
        if constexpr (EPI == 1) {
          const float v = acc[m][n][r] + bias[col];
          ((unsigned short*)outp)[(size_t)row * N + col] = f2bf(fmaxf(v, 0.f));
        } else {
          unsigned short* dst = (unsigned short*)(bz ? part : outp);
          dst[(size_t)row * N + col] = f2bf(acc[m][n][r]);
        }
      }
    }
  }
}

// ---------------- flash attention v5: v4 + T15 att[2] double-pipeline -----------
// Two score tiles live: exp/P-store of tile t (VALU+trans) overlaps QK^T of tile
// t+1 (MFMA pipe). kf loaded 2 tiles ahead; Vt staging/barrier/vmcnt(8) exactly
// as v4 (10 outstanding at wait: 8 K newer + 2 Vt oldest -> vmcnt(8) retires Vt).
__global__ __launch_bounds__(256, 2) void attn_kernel(const unsigned short* __restrict__ q,
                                                      const unsigned short* __restrict__ k,
                                                      const unsigned short* __restrict__ vt,
                                                      unsigned short* __restrict__ o) {
  const int bh = blockIdx.x;
  const int q0 = blockIdx.y * 128;
  const unsigned short* qh = q + (size_t)bh * 2048 * 64;
  const unsigned short* kh = k + (size_t)bh * 2048 * 64;
  const unsigned short* vh = vt + (size_t)bh * 64 * 2048;  // [d][s]
  const int wid = threadIdx.x >> 6, lane = threadIdx.x & 63;
  const int lr = lane & 15, lg = lane >> 4;
  const int qw = q0 + wid * 32;

  __shared__ __align__(16) unsigned short Vt[2][64 * 64];
  __shared__ __align__(16) unsigned short Ps[4][32 * 64];

  constexpr float CS = 0.125f * 1.4426950408889634f;
  short8 qf[2][2];
#pragma unroll
  for (int m = 0; m < 2; ++m)
#pragma unroll
    for (int kk = 0; kk < 2; ++kk) {
      short8 t = *(const short8*)&qh[(size_t)(qw + m * 16 + lr) * 64 + kk * 32 + lg * 8];
#pragma unroll
      for (int j = 0; j < 8; ++j) t[j] = (short)f2bf(bf2f((unsigned short)t[j]) * CS);
      qf[m][kk] = t;
    }

  f32x4 po[2][4];
  float lrun[2][4];
#pragma unroll
  for (int m = 0; m < 2; ++m) {
#pragma unroll
    for (int n = 0; n < 4; ++n) po[m][n] = (f32x4){0.f, 0.f, 0.f, 0.f};
#pragma unroll
    for (int r = 0; r < 4; ++r) lrun[m][r] = 0.f;
  }

  const int scol = ((lane & 7) ^ ((lane >> 3) & 7)) * 8;
  char* const PsB = (char*)&Ps[wid][0];

  short8 kfA[4][2], kfB[4][2];
  f32x4 scA[2][4], scB[2][4];

#define LOAD_K(KF, kt)                                                                   \
  {                                                                                      \
    _Pragma("unroll") for (int n = 0; n < 4; ++n) _Pragma("unroll") for (int kk = 0;     \
                                                                         kk < 2; ++kk)  \
        KF[n][kk] =                                                                      \
        *(const short8*)&kh[(size_t)((kt) + n * 16 + lr) * 64 + kk * 32 + lg * 8];       \
  }
#define STAGE_VT(BUF, kt)                                                                \
  {                                                                                      \
    _Pragma("unroll") for (int i = 0; i < 2; ++i) {                                      \
      const int r = (wid * 2 + i) * 8;                                                   \
      gload_lds16(vh + (size_t)(r + (lane >> 3)) * 2048 + (kt) + scol,                   \
                  (void*)&Vt[BUF][r * 64]);                                              \
    }                                                                                    \
  }
#define QKT(SC, KF)                                                                      \
  {                                                                                      \
    _Pragma("unroll") for (int m = 0; m < 2; ++m) _Pragma("unroll") for (int n = 0;      \
                                                                         n < 4; ++n)    \
        SC[m][n] = (f32x4){0.f, 0.f, 0.f, 0.f};                                          \
    __builtin_amdgcn_s_setprio(1);                                                       \
    _Pragma("unroll") for (int kk = 0; kk < 2; ++kk)                                     \
        _Pragma("unroll") for (int m = 0; m < 2; ++m)                                    \
        _Pragma("unroll") for (int n = 0; n < 4; ++n)                                    \
        SC[m][n] = MFMA_BF16(qf[m][kk], KF[n][kk], SC[m][n]);                            \
    __builtin_amdgcn_s_setprio(0);                                                       \
  }
#define EXPP(SC)                                                                         \
  {                                                                                      \
    _Pragma("unroll") for (int m = 0; m < 2; ++m)                                        \
        _Pragma("unroll") for (int r = 0; r < 4; ++r) {                                  \
      const float p0 = __builtin_amdgcn_exp2f(SC[m][0][r]);                              \
      const float p1 = __builtin_amdgcn_exp2f(SC[m][1][r]);                              \
      const float p2 = __builtin_amdgcn_exp2f(SC[m][2][r]);                              \
      const float p3 = __builtin_amdgcn_exp2f(SC[m][3][r]);                              \
      lrun[m][r] += (p0 + p1) + (p2 + p3);                                               \
      unsigned int u0, u1;                                                               \
      asm("v_cvt_pk_bf16_f32 %0, %1, %2" : "=v"(u0) : "v"(p0), "v"(p1));                 \
      asm("v_cvt_pk_bf16_f32 %0, %1, %2" : "=v"(u1) : "v"(p2), "v"(p3));                 \
      const int row = m * 16 + lg * 4 + r;                                               \
      uint2 pk2; pk2.x = u0; pk2.y = u1;                                                 \
      *(uint2*)(PsB + row * 128 + ((lr * 8) ^ ((row & 7) << 4))) = pk2;                  \
    }                                                                                    \
  }
#define PV(BUF)                                                                          \
  {                                                                                      \
    _Pragma("unroll") for (int kk = 0; kk < 2; ++kk) {                                   \
      const int coff = kk * 64 + lg * 16;                                                \
      short8 pa[2], vbr[4];                                                              \
      _Pragma("unroll") for (int m = 0; m < 2; ++m) {                                    \
        const int prow = m * 16 + lr;                                                    \
        pa[m] = *(const short8*)(PsB + prow * 128 + (coff ^ ((prow & 7) << 4)));         \
      }                                                                                  \
      _Pragma("unroll") for (int n = 0; n < 4; ++n)                                      \
        vbr[n] = lds_swz_read(&Vt[BUF][0], n * 16 + lr, coff);                           \
      __builtin_amdgcn_s_setprio(1);                                                     \
      _Pragma("unroll") for (int m = 0; m < 2; ++m)                                      \
          _Pragma("unroll") for (int n = 0; n < 4; ++n)                                  \
          po[m][n] = MFMA_BF16(pa[m], vbr[n], po[m][n]);                                 \
      __builtin_amdgcn_s_setprio(0);                                                     \
    }                                                                                    \
  }

  // prologue: kf(0), Vt(0), kf(1), sc(0)
  LOAD_K(kfA, 0)
  STAGE_VT(0, 0)
  LOAD_K(kfB, 64)
  QKT(scA, kfA)

  // body: consume SCe=sc(t); compute SCf=sc(t+1) from KN; load KL=kf(t+2);
  // stage Vt[BUF^1] for t+1; PV(t) from Vt[BUF].
#define STEP(KN, KL, SCe, SCf, BUF, t)                                                   \
  {                                                                                      \
    QKT(SCf, KN)                                                                         \
    const int kt2 = ((t) + 2 < 32) ? ((t) + 2) * 64 : 0;                                 \
    LOAD_K(KL, kt2)                                                                      \
    EXPP(SCe)                                                                            \
    asm volatile("s_waitcnt vmcnt(8) lgkmcnt(0)" ::: "memory");                          \
    __builtin_amdgcn_s_barrier();                                                        \
    __builtin_amdgcn_sched_barrier(0);                                                   \
    const int ktn = ((t) + 1 < 32) ? ((t) + 1) * 64 : 0;                                 \
    STAGE_VT(BUF ^ 1, ktn)                                                               \
    __builtin_amdgcn_sched_barrier(0);                                                   \
    PV(BUF)                                                                              \
  }

  for (int t = 0; t < 30; t += 2) {
    STEP(kfB, kfA, scA, scB, 0, t)
    STEP(kfA, kfB, scB, scA, 1, t + 1)
  }
  // t=30: consume sc(30)=scA, compute sc(31)=scB, stage Vt[1] for 31
  STEP(kfB, kfA, scA, scB, 0, 30)
  // tail t=31: exp(31) + PV(31), no further staging
  EXPP(scB)
  asm volatile("s_waitcnt vmcnt(0) lgkmcnt(0)" ::: "memory");
  __builtin_amdgcn_s_barrier();
  __builtin_amdgcn_sched_barrier(0);
  PV(1)
#undef STEP
#undef PV
#undef EXPP
#undef QKT
#undef LOAD_K
#undef STAGE_VT

#pragma unroll
  for (int d = 1; d < 16; d <<= 1)
#pragma unroll
    for (int m = 0; m < 2; ++m)
#pragma unroll
      for (int r = 0; r < 4; ++r) lrun[m][r] += __shfl_xor(lrun[m][r], d);

  const int b = bh >> 4, hh = bh & 15;
#pragma unroll
  for (int m = 0; m < 2; ++m)
#pragma unroll
    for (int n = 0; n < 4; ++n)
#pragma unroll
      for (int r = 0; r < 4; ++r) {
        const int qrow = qw + m * 16 + lg * 4 + r;
        const int d = n * 16 + lr;
        o[((size_t)b * 2048 + qrow) * 1024 + hh * 64 + d] =
            f2bf(po[m][n][r] / lrun[m][r]);
      }
}

// ---------------- launcher ----------------
extern "C" void kernel_launch(void* const* d_in, const int* in_sizes, int n_in,
                              void* d_out, int out_size, void* d_ws, size_t ws_size,
                              hipStream_t stream) {
  const float* x  = (const float*)d_in[0];
  const float* Wq = (const float*)d_in[1];
  const float* bq = (const float*)d_in[2];
  const float* Wk = (const float*)d_in[3];
  const float* bk = (const float*)d_in[4];
  const float* Wv = (const float*)d_in[5];
  const float* bv = (const float*)d_in[6];
  const float* Wo = (const float*)d_in[7];
  const float* bo = (const float*)d_in[8];
  const float* W1 = (const float*)d_in[9];
  const float* b1 = (const float*)d_in[10];
  const float* W2 = (const float*)d_in[11];
  const float* b2 = (const float*)d_in[12];
  const float* g1 = (const float*)d_in[13];
  const float* be1 = (const float*)d_in[14];
  const float* g2 = (const float*)d_in[15];
  const float* be2 = (const float*)d_in[16];

  char* ws = (char*)d_ws;
  const size_t MB = 1024 * 1024;
  unsigned short* Wqkv_b = (unsigned short*)(ws + 0 * MB);
  unsigned short* Wo_b   = (unsigned short*)(ws + 6 * MB);
  unsigned short* W1_b   = (unsigned short*)(ws + 8 * MB);
  unsigned short* W2_b   = (unsigned short*)(ws + 16 * MB);
  unsigned short* h_b    = (unsigned short*)(ws + 24 * MB);
  unsigned short* qb     = (unsigned short*)(ws + 32 * MB);  // q|k|v^T contiguous
  unsigned short* ab     = (unsigned short*)(ws + 56 * MB);
  float*          x1     = (float*)(ws + 64 * MB);
  unsigned short* fb     = (unsigned short*)(ws + 32 * MB);  // reuse q/k/v region
  unsigned short* p0     = (unsigned short*)(ws + 0 * MB);   // FFN2 partial 0 (8 MB)
  unsigned short* p1     = (unsigned short*)(ws + 8 * MB);   // FFN2 partial 1 (8 MB)

  // weight conversions + LN1 fused into one launch
  cvt_ln<<<16384, 256, 0, stream>>>(Wq, Wk, Wv, Wo, W1, W2, Wqkv_b, Wo_b, W1_b, W2_b,
                                    x, g1, be1, h_b);

  // fused QKV projection (EPI 0: q,k permuted; v transposed+sigma, coalesced)
  gemm_bf16<128, 0><<<768, 256, 0, stream>>>(h_b, Wqkv_b, bq, bk, bv, nullptr, qb,
                                             4096, 3072, 1024, 24, 32, 1024);

  // attention: x = head (XCD locality), y = q-block (QBLK=128)
  attn_kernel<<<dim3(32, 16), 256, 0, stream>>>(qb, qb + 4194304, qb + 2 * 4194304, ab);

  // O-proj + residual -> x1 (fp32)
  gemm_bf16<64, 2, 3><<<512, 256, 0, stream>>>(ab, Wo_b, bo, nullptr, nullptr, x, x1,
                                               4096, 1024, 1024, 16, 32, 1024);

  // LN2
  ln_kernel<<<4096, 256, 0, stream>>>(x1, g2, be2, h_b);

  // FFN1 (relu, bf16), 256^2 tiles, 8 waves
  gemm256<256, 256, 1><<<256, 512, 0, stream>>>(h_b, W1_b, b1, nullptr, fb,
                                                4096, 4096, 1024, 16, 16, 1024);

  // FFN2 split-K=2, bf16 raw partials (slice0 -> p0, slice1 -> p1)
  gemm256<128, 256, 4><<<256, 512, 0, stream>>>(fb, W2_b, nullptr, p1, p0,
                                                4096, 1024, 4096, 4, 32, 2048);

  // final reduce: d_out = p0 + p1 + x1 + b2
  ffn2_reduce<<<4096, 256, 0, stream>>>((float*)d_out, p0, p1, x1, b2);
}

// Round 22
// 229.833 us; speedup vs baseline: 1.1143x; 1.0079x over previous
//
#include <hip/hip_runtime.h>

typedef __attribute__((ext_vector_type(8))) short short8;
typedef __attribute__((ext_vector_type(4))) float f32x4;
typedef __attribute__((ext_vector_type(4))) unsigned short us4;

#define MFMA_BF16(a, b, c) __builtin_amdgcn_mfma_f32_16x16x32_bf16((a), (b), (c), 0, 0, 0)

__device__ __forceinline__ unsigned short f2bf(float f) {
  union { float f; unsigned int u; } x; x.f = f;
  unsigned int r = x.u + 0x7FFFu + ((x.u >> 16) & 1u);
  return (unsigned short)(r >> 16);
}
__device__ __forceinline__ float bf2f(unsigned short b) {
  union { float f; unsigned int u; } x; x.u = ((unsigned int)b) << 16;
  return x.f;
}

typedef __attribute__((address_space(3))) unsigned int lds_uint;
typedef const __attribute__((address_space(1))) unsigned int gbl_uint;

__device__ __forceinline__ void gload_lds16(const void* g, void* l) {
  __builtin_amdgcn_global_load_lds((gbl_uint*)g, (lds_uint*)l, 16, 0, 0);
}

// swizzled LDS read: row stride 128 B, colbyte XOR'd with (row&7)<<4
__device__ __forceinline__ short8 lds_swz_read(const unsigned short* base, int row, int colbyte) {
  return *(const short8*)((const char*)base + row * 128 + (colbyte ^ ((row & 7) << 4)));
}

// ------ fused: weight fp32->bf16 convert (blocks 0..12287) + LN1 (12288..16383) --
__global__ __launch_bounds__(256) void cvt_ln(const float* __restrict__ Wq,
                                              const float* __restrict__ Wk,
                                              const float* __restrict__ Wv,
                                              const float* __restrict__ Wo,
                                              const float* __restrict__ W1,
                                              const float* __restrict__ W2,
                                              unsigned short* __restrict__ Wqkv_b,
                                              unsigned short* __restrict__ Wo_b,
                                              unsigned short* __restrict__ W1_b,
                                              unsigned short* __restrict__ W2_b,
                                              const float* __restrict__ x,
                                              const float* __restrict__ g,
                                              const float* __restrict__ be,
                                              unsigned short* __restrict__ lnout) {
  const int b = blockIdx.x;
  const int t = threadIdx.x;
  __shared__ float red[8];
  if (b < 12288) {
    const float* src;
    unsigned short* dst;
    int off;
    if (b < 1024)      { src = Wq; dst = Wqkv_b;           off = b; }
    else if (b < 2048) { src = Wk; dst = Wqkv_b + 1048576; off = b - 1024; }
    else if (b < 3072) { src = Wv; dst = Wqkv_b + 2097152; off = b - 2048; }
    else if (b < 4096) { src = Wo; dst = Wo_b;             off = b - 3072; }
    else if (b < 8192) { src = W1; dst = W1_b;             off = b - 4096; }
    else               { src = W2; dst = W2_b;             off = b - 8192; }
    const int i = off * 256 + t;
    const float4 v = ((const float4*)src)[i];
    us4 o;
    o.x = f2bf(v.x); o.y = f2bf(v.y); o.z = f2bf(v.z); o.w = f2bf(v.w);
    ((us4*)dst)[i] = o;
    return;
  }
  const int row = b - 12288;
  const float4 v = ((const float4*)(x + (size_t)row * 1024))[t];
  float s = v.x + v.y + v.z + v.w;
  float s2 = v.x * v.x + v.y * v.y + v.z * v.z + v.w * v.w;
#pragma unroll
  for (int d = 1; d < 64; d <<= 1) {
    s += __shfl_xor(s, d);
    s2 += __shfl_xor(s2, d);
  }
  const int wid = t >> 6, lane = t & 63;
  if (lane == 0) { red[wid] = s; red[4 + wid] = s2; }
  __syncthreads();
  s = red[0] + red[1] + red[2] + red[3];
  s2 = red[4] + red[5] + red[6] + red[7];
  const float mu = s * (1.0f / 1024.0f);
  const float var = s2 * (1.0f / 1024.0f) - mu * mu;
  const float rstd = rsqrtf(var + 1e-5f);
  const float4 gv = ((const float4*)g)[t];
  const float4 bv = ((const float4*)be)[t];
  us4 o;
  o.x = f2bf((v.x - mu) * rstd * gv.x + bv.x);
  o.y = f2bf((v.y - mu) * rstd * gv.y + bv.y);
  o.z = f2bf((v.z - mu) * rstd * gv.z + bv.z);
  o.w = f2bf((v.w - mu) * rstd * gv.w + bv.w);
  ((us4*)(lnout + (size_t)row * 1024))[t] = o;
}

// ---------------- layernorm, bf16 input: bf16 in -> bf16 out (1024 cols) --------
// 256 threads x 4 bf16 each = 1024 cols (matches the fp32 version's coverage).
__global__ __launch_bounds__(256) void ln_kernel_b(const unsigned short* __restrict__ xb,
                                                   const float* __restrict__ g,
                                                   const float* __restrict__ be,
                                                   unsigned short* __restrict__ out) {
  const int row = blockIdx.x;
  const int t = threadIdx.x;
  const us4 v4 = *(const us4*)(xb + (size_t)row * 1024 + t * 4);
  float v0 = bf2f(v4.x), v1 = bf2f(v4.y), v2 = bf2f(v4.z), v3 = bf2f(v4.w);
  float s = v0 + v1 + v2 + v3;
  float s2 = v0 * v0 + v1 * v1 + v2 * v2 + v3 * v3;
#pragma unroll
  for (int d = 1; d < 64; d <<= 1) {
    s += __shfl_xor(s, d);
    s2 += __shfl_xor(s2, d);
  }
  __shared__ float red[8];
  const int wid = t >> 6, lane = t & 63;
  if (lane == 0) { red[wid] = s; red[4 + wid] = s2; }
  __syncthreads();
  s = red[0] + red[1] + red[2] + red[3];
  s2 = red[4] + red[5] + red[6] + red[7];
  const float mu = s * (1.0f / 1024.0f);
  const float var = s2 * (1.0f / 1024.0f) - mu * mu;
  const float rstd = rsqrtf(var + 1e-5f);
  const float4 gv = ((const float4*)g)[t];
  const float4 bv = ((const float4*)be)[t];
  us4 o;
  o.x = f2bf((v0 - mu) * rstd * gv.x + bv.x);
  o.y = f2bf((v1 - mu) * rstd * gv.y + bv.y);
  o.z = f2bf((v2 - mu) * rstd * gv.z + bv.z);
  o.w = f2bf((v3 - mu) * rstd * gv.w + bv.w);
  *(us4*)(out + (size_t)row * 1024 + t * 4) = o;
}

// ---------------- FFN2 reduce: out = bf16(p0)+bf16(p1) + bf16(x1) + b2 ----------
__global__ __launch_bounds__(256) void ffn2_reduce(float* __restrict__ out,
                                                   const unsigned short* __restrict__ p0,
                                                   const unsigned short* __restrict__ p1,
                                                   const unsigned short* __restrict__ x1b,
                                                   const float* __restrict__ b2) {
  const int row = blockIdx.x, t = threadIdx.x;
  const size_t i = (size_t)row * 256 + t;
  const us4 a0 = ((const us4*)p0)[i];
  const us4 a1 = ((const us4*)p1)[i];
  const us4 c = ((const us4*)x1b)[i];
  const float4 b = ((const float4*)b2)[t];
  float4 v;
  v.x = bf2f(a0.x) + bf2f(a1.x) + bf2f(c.x) + b.x;
  v.y = bf2f(a0.y) + bf2f(a1.y) + bf2f(c.y) + b.y;
  v.z = bf2f(a0.z) + bf2f(a1.z) + bf2f(c.z) + b.z;
  v.w = bf2f(a0.w) + bf2f(a1.w) + bf2f(c.w) + b.w;
  ((float4*)out)[i] = v;
}

// ---------------- GEMM (4-wave, 128-row tiles): counted-vmcnt + T2 swizzle ------
// EPI 0: fused-QKV store (q,k permuted; v transposed+sigma via LDS, coalesced).
// EPI 1: relu bf16; EPI 2: +res(fp32), store BF16.
template <int BN, int EPI, int MINW = 2>
__global__ __launch_bounds__(256, MINW) void gemm_bf16(const unsigned short* __restrict__ A,
                                                       const unsigned short* __restrict__ B,
                                                       const float* __restrict__ bias,
                                                       const float* __restrict__ biasK,
                                                       const float* __restrict__ biasV,
                                                       const float* __restrict__ res,
                                                       void* __restrict__ outp,
                                                       int M, int N, int K,
                                                       int gx, int gy, int kspl) {
  constexpr int WN = (BN == 128) ? 2 : 1;
  constexpr int WROWS = 128 / (4 / WN);
  constexpr int MW = WROWS / 16;
  constexpr int NW = (BN / WN) / 16;
  constexpr int BCH = BN / 32;
  constexpr int LOADS = 4 + BCH;

  __shared__ __align__(16) unsigned short SMEM[2 * 128 * 64 + 2 * BN * 64];
  auto As = (unsigned short(*)[128 * 64])SMEM;
  auto Bs = (unsigned short(*)[BN * 64])(SMEM + 2 * 128 * 64);

  const int nwg = gridDim.x;
  const int id2 = ((int)blockIdx.x & 7) * (nwg >> 3) + ((int)blockIdx.x >> 3);
  const int bx = id2 % gx;
  const int byz = id2 / gx;
  const int by = byz % gy;
  const int bz = byz / gy;

  const int wid = threadIdx.x >> 6;
  const int lane = threadIdx.x & 63;
  const int lr = lane & 15, lg = lane >> 4;
  const int row0 = by * 128;
  const int col0 = bx * BN;
  const int k0 = bz * kspl;
  const int wm = (wid / WN) * WROWS;
  const int wn = (wid % WN) * (BN / WN);

  const int scol = ((lane & 7) ^ ((lane >> 3) & 7)) * 8;

  auto stage = [&](int buf, int kt) {
#pragma unroll
    for (int i = 0; i < 4; ++i) {
      const int r = wid * 32 + i * 8;
      gload_lds16(A + (size_t)(row0 + r + (lane >> 3)) * K + kt + scol,
                  (void*)&As[buf][r * 64]);
    }
#pragma unroll
    for (int i = 0; i < BCH; ++i) {
      const int r = wid * (8 * BCH) + i * 8;
      gload_lds16(B + (size_t)(col0 + r + (lane >> 3)) * K + kt + scol,
                  (void*)&Bs[buf][r * 64]);
    }
  };

  f32x4 acc[MW][NW];
#pragma unroll
  for (int m = 0; m < MW; ++m)
#pragma unroll
    for (int n = 0; n < NW; ++n) acc[m][n] = (f32x4){0.f, 0.f, 0.f, 0.f};

  auto mma = [&](int buf) {
#pragma unroll
    for (int kk = 0; kk < 64; kk += 32) {
      const int colbyte = kk * 2 + lg * 16;
      short8 av[MW], bv[NW];
#pragma unroll
      for (int m = 0; m < MW; ++m)
        av[m] = lds_swz_read(&As[buf][0], wm + m * 16 + lr, colbyte);
#pragma unroll
      for (int n = 0; n < NW; ++n)
        bv[n] = lds_swz_read(&Bs[buf][0], wn + n * 16 + lr, colbyte);
#pragma unroll
      for (int m = 0; m < MW; ++m)
#pragma unroll
        for (int n = 0; n < NW; ++n) acc[m][n] = MFMA_BF16(av[m], bv[n], acc[m][n]);
    }
  };

  stage(0, k0);
  stage(1, k0 + 64);
  const int ktend = k0 + kspl;
  int cur = 0;
  for (int kt = k0; kt < ktend - 64; kt += 64) {
    asm volatile("s_waitcnt vmcnt(%0)" ::"i"(LOADS) : "memory");
    __builtin_amdgcn_s_barrier();
    __builtin_amdgcn_sched_barrier(0);
    mma(cur);
    __builtin_amdgcn_s_barrier();
    if (kt + 128 < ktend) stage(cur, kt + 128);
    cur ^= 1;
  }
  asm volatile("s_waitcnt vmcnt(0)" ::: "memory");
  __builtin_amdgcn_s_barrier();
  __builtin_amdgcn_sched_barrier(0);
  mma(cur);

  if constexpr (EPI == 0) {
    const int which = col0 >> 10;  // uniform per block (col0 multiple of 128)
    if (which < 2) {
#pragma unroll
      for (int m = 0; m < MW; ++m)
#pragma unroll
        for (int n = 0; n < NW; ++n)
#pragma unroll
          for (int r = 0; r < 4; ++r) {
            const int row = row0 + wm + m * 16 + lg * 4 + r;
            const int col = col0 + wn + n * 16 + lr;
            const int c = col & 1023;
            const float* bp = (which == 0) ? bias : biasK;
            const float v = acc[m][n][r] + bp[c];
            const size_t idx = (size_t)which * 4194304 +
                ((((size_t)(row >> 11)) * 16 + (c >> 6)) * 2048 + (row & 2047)) * 64 +
                (c & 63);
            ((unsigned short*)outp)[idx] = f2bf(v);
          }
    } else {
      // V tile: sigma-permuted transpose via reused LDS, then coalesced V^T store
      unsigned short* Vlds = SMEM;
      __syncthreads();
#pragma unroll
      for (int m = 0; m < MW; ++m)
#pragma unroll
        for (int n = 0; n < NW; ++n)
#pragma unroll
          for (int r = 0; r < 4; ++r) {
            const int rl = wm + m * 16 + lg * 4 + r;
            const int xx = rl & 63;
            const int rs = (rl & ~63) | ((xx & 15) << 2) | (xx >> 4);
            const int coll = wn + n * 16 + lr;
            const float v = acc[m][n][r] + biasV[(col0 & 1023) + coll];
            Vlds[coll * 144 + rs] = f2bf(v);
          }
      __syncthreads();
      const int cl = threadIdx.x >> 1, h = threadIdx.x & 1;
      const int c = (col0 & 1023) + cl;
      const int bb = row0 >> 11;
      unsigned short* vdst = (unsigned short*)outp + (size_t)2 * 4194304 +
          (((size_t)bb * 16 + (c >> 6)) * 64 + (c & 63)) * 2048 + (row0 & 2047) + h * 64;
#pragma unroll
      for (int w = 0; w < 8; ++w)
        *(short8*)(vdst + w * 8) = *(const short8*)&Vlds[cl * 144 + h * 64 + w * 8];
    }
  } else {
#pragma unroll
    for (int m = 0; m < MW; ++m) {
#pragma unroll
      for (int n = 0; n < NW; ++n) {
#pragma unroll
        for (int r = 0; r < 4; ++r) {
          const int row = row0 + wm + m * 16 + lg * 4 + r;
          const int col = col0 + wn + n * 16 + lr;
          if constexpr (EPI == 1) {
            const float v = acc[m][n][r] + bias[col];
            ((unsigned short*)outp)[(size_t)row * N + col] = f2bf(fmaxf(v, 0.f));
          } else {
            const float v = acc[m][n][r] + bias[col] + res[(size_t)row * N + col];
            ((unsigned short*)outp)[(size_t)row * N + col] = f2bf(v);
          }
        }
      }
    }
  }
}

// ---------------- GEMM (8-wave, BMxBN tiles): counted-vmcnt + T2 swizzle --------
template <int BM, int BN, int EPI>
__global__ __launch_bounds__(512, 2) void gemm256(const unsigned short* __restrict__ A,
                                                  const unsigned short* __restrict__ B,
                                                  const float* __restrict__ bias,
                                                  void* __restrict__ part,
                                                  void* __restrict__ outp,
                                                  int M, int N, int K,
                                                  int gx, int gy, int kspl) {
  constexpr int MW = BM / 32;
  constexpr int NW = BN / 64;
  constexpr int A_ISS = BM / 64;
  constexpr int B_ISS = BN / 64;
  constexpr int LOADS = A_ISS + B_ISS;

  __shared__ __align__(16) unsigned short As[2][BM * 64];
  __shared__ __align__(16) unsigned short Bs[2][BN * 64];

  const int nwg = gridDim.x;
  const int id2 = ((int)blockIdx.x & 7) * (nwg >> 3) + ((int)blockIdx.x >> 3);
  const int bx = id2 % gx;
  const int byz = id2 / gx;
  const int by = byz % gy;
  const int bz = byz / gy;

  const int wid = threadIdx.x >> 6;
  const int lane = threadIdx.x & 63;
  const int lr = lane & 15, lg = lane >> 4;
  const int wr = wid >> 2, wc = wid & 3;
  const int row0 = by * BM;
  const int col0 = bx * BN;
  const int k0 = bz * kspl;
  const int wm = wr * (BM / 2);
  const int wn = wc * (BN / 4);

  const int scol = ((lane & 7) ^ ((lane >> 3) & 7)) * 8;

  auto stage = [&](int buf, int kt) {
#pragma unroll
    for (int i = 0; i < A_ISS; ++i) {
      const int r = wid * 8 + i * 64;
      gload_lds16(A + (size_t)(row0 + r + (lane >> 3)) * K + kt + scol,
                  (void*)&As[buf][r * 64]);
    }
#pragma unroll
    for (int i = 0; i < B_ISS; ++i) {
      const int r = wid * 8 + i * 64;
      gload_lds16(B + (size_t)(col0 + r + (lane >> 3)) * K + kt + scol,
                  (void*)&Bs[buf][r * 64]);
    }
  };

  f32x4 acc[MW][NW];
#pragma unroll
  for (int m = 0; m < MW; ++m)
#pragma unroll
    for (int n = 0; n < NW; ++n) acc[m][n] = (f32x4){0.f, 0.f, 0.f, 0.f};

  auto mma = [&](int buf) {
#pragma unroll
    for (int kk = 0; kk < 64; kk += 32) {
      const int colbyte = kk * 2 + lg * 16;
      short8 av[MW], bv[NW];
#pragma unroll
      for (int m = 0; m < MW; ++m)
        av[m] = lds_swz_read(&As[buf][0], wm + m * 16 + lr, colbyte);
#pragma unroll
      for (int n = 0; n < NW; ++n)
        bv[n] = lds_swz_read(&Bs[buf][0], wn + n * 16 + lr, colbyte);
#pragma unroll
      for (int m = 0; m < MW; ++m)
#pragma unroll
        for (int n = 0; n < NW; ++n) acc[m][n] = MFMA_BF16(av[m], bv[n], acc[m][n]);
    }
  };

  stage(0, k0);
  stage(1, k0 + 64);
  const int ktend = k0 + kspl;
  int cur = 0;
  for (int kt = k0; kt < ktend - 64; kt += 64) {
    asm volatile("s_waitcnt vmcnt(%0)" ::"i"(LOADS) : "memory");
    __builtin_amdgcn_s_barrier();
    __builtin_amdgcn_sched_barrier(0);
    mma(cur);
    __builtin_amdgcn_s_barrier();
    if (kt + 128 < ktend) stage(cur, kt + 128);
    cur ^= 1;
  }
  asm volatile("s_waitcnt vmcnt(0)" ::: "memory");
  __builtin_amdgcn_s_barrier();
  __builtin_amdgcn_sched_barrier(0);
  mma(cur);

#pragma unroll
  for (int m = 0; m < MW; ++m) {
#pragma unroll
    for (int n = 0; n < NW; ++n) {
#pragma unroll
      for (int r = 0; r < 4; ++r) {
        const int row = row0 + wm + m * 16 + lg * 4 + r;
        const int col = col0 + wn + n * 16 + lr;
        if constexpr (EPI == 1) {
          const float v = acc[m][n][r] + bias[col];
          ((unsigned short*)outp)[(size_t)row * N + col] = f2bf(fmaxf(v, 0.f));
        } else {
          unsigned short* dst = (unsigned short*)(bz ? part : outp);
          dst[(size_t)row * N + col] = f2bf(acc[m][n][r]);
        }
      }
    }
  }
}

// ---------------- flash attention v5 (frozen R20 config, +rcp hoist) ------------
__global__ __launch_bounds__(256, 2) void attn_kernel(const unsigned short* __restrict__ q,
                                                      const unsigned short* __restrict__ k,
                                                      const unsigned short* __restrict__ vt,
                                                      unsigned short* __restrict__ o) {
  const int bh = blockIdx.x;
  const int q0 = blockIdx.y * 128;
  const unsigned short* qh = q + (size_t)bh * 2048 * 64;
  const unsigned short* kh = k + (size_t)bh * 2048 * 64;
  const unsigned short* vh = vt + (size_t)bh * 64 * 2048;  // [d][s]
  const int wid = threadIdx.x >> 6, lane = threadIdx.x & 63;
  const int lr = lane & 15, lg = lane >> 4;
  const int qw = q0 + wid * 32;

  __shared__ __align__(16) unsigned short Vt[2][64 * 64];
  __shared__ __align__(16) unsigned short Ps[4][32 * 64];

  constexpr float CS = 0.125f * 1.4426950408889634f;
  short8 qf[2][2];
#pragma unroll
  for (int m = 0; m < 2; ++m)
#pragma unroll
    for (int kk = 0; kk < 2; ++kk) {
      short8 t = *(const short8*)&qh[(size_t)(qw + m * 16 + lr) * 64 + kk * 32 + lg * 8];
#pragma unroll
      for (int j = 0; j < 8; ++j) t[j] = (short)f2bf(bf2f((unsigned short)t[j]) * CS);
      qf[m][kk] = t;
    }

  f32x4 po[2][4];
  float lrun[2][4];
#pragma unroll
  for (int m = 0; m < 2; ++m) {
#pragma unroll
    for (int n = 0; n < 4; ++n) po[m][n] = (f32x4){0.f, 0.f, 0.f, 0.f};
#pragma unroll
    for (int r = 0; r < 4; ++r) lrun[m][r] = 0.f;
  }

  const int scol = ((lane & 7) ^ ((lane >> 3) & 7)) * 8;
  char* const PsB = (char*)&Ps[wid][0];

  short8 kfA[4][2], kfB[4][2];
  f32x4 scA[2][4], scB[2][4];

#define LOAD_K(KF, kt)                                                                   \
  {                                                                                      \
    _Pragma("unroll") for (int n = 0; n < 4; ++n) _Pragma("unroll") for (int kk = 0;     \
                                                                         kk < 2; ++kk)  \
        KF[n][kk] =                                                                      \
        *(const short8*)&kh[(size_t)((kt) + n * 16 + lr) * 64 + kk * 32 + lg * 8];       \
  }
#define STAGE_VT(BUF, kt)                                                                \
  {                                                                                      \
    _Pragma("unroll") for (int i = 0; i < 2; ++i) {                                      \
      const int r = (wid * 2 + i) * 8;                                                   \
      gload_lds16(vh + (size_t)(r + (lane >> 3)) * 2048 + (kt) + scol,                   \
                  (void*)&Vt[BUF][r * 64]);                                              \
    }                                                                                    \
  }
#define QKT(SC, KF)                                                                      \
  {                                                                                      \
    _Pragma("unroll") for (int m = 0; m < 2; ++m) _Pragma("unroll") for (int n = 0;      \
                                                                         n < 4; ++n)    \
        SC[m][n] = (f32x4){0.f, 0.f, 0.f, 0.f};                                          \
    __builtin_amdgcn_s_setprio(1);                                                       \
    _Pragma("unroll") for (int kk = 0; kk < 2; ++kk)                                     \
        _Pragma("unroll") for (int m = 0; m < 2; ++m)                                    \
        _Pragma("unroll") for (int n = 0; n < 4; ++n)                                    \
        SC[m][n] = MFMA_BF16(qf[m][kk], KF[n][kk], SC[m][n]);                            \
    __builtin_amdgcn_s_setprio(0);                                                       \
  }
#define EXPP(SC)                                                                         \
  {                                                                                      \
    _Pragma("unroll") for (int m = 0; m < 2; ++m)                                        \
        _Pragma("unroll") for (int r = 0; r < 4; ++r) {                                  \
      const float p0 = __builtin_amdgcn_exp2f(SC[m][0][r]);                              \
      const float p1 = __builtin_amdgcn_exp2f(SC[m][1][r]);                              \
      const float p2 = __builtin_amdgcn_exp2f(SC[m][2][r]);                              \
      const float p3 = __builtin_amdgcn_exp2f(SC[m][3][r]);                              \
      lrun[m][r] += (p0 + p1) + (p2 + p3);                                               \
      unsigned int u0, u1;                                                               \
      asm("v_cvt_pk_bf16_f32 %0, %1, %2" : "=v"(u0) : "v"(p0), "v"(p1));                 \
      asm("v_cvt_pk_bf16_f32 %0, %1, %2" : "=v"(u1) : "v"(p2), "v"(p3));                 \
      const int row = m * 16 + lg * 4 + r;                                               \
      uint2 pk2; pk2.x = u0; pk2.y = u1;                                                 \
      *(uint2*)(PsB + row * 128 + ((lr * 8) ^ ((row & 7) << 4))) = pk2;                  \
    }                                                                                    \
  }
#define PV(BUF)                                                                          \
  {                                                                                      \
    _Pragma("unroll") for (int kk = 0; kk < 2; ++kk) {                                   \
      const int coff = kk * 64 + lg * 16;                                                \
      short8 pa[2], vbr[4];                                                              \
      _Pragma("unroll") for (int m = 0; m < 2; ++m) {                                    \
        const int prow = m * 16 + lr;                                                    \
        pa[m] = *(const short8*)(PsB + prow * 128 + (coff ^ ((prow & 7) << 4)));         \
      }                                                                                  \
      _Pragma("unroll") for (int n = 0; n < 4; ++n)                                      \
        vbr[n] = lds_swz_read(&Vt[BUF][0], n * 16 + lr, coff);                           \
      __builtin_amdgcn_s_setprio(1);                                                     \
      _Pragma("unroll") for (int m = 0; m < 2; ++m)                                      \
          _Pragma("unroll") for (int n = 0; n < 4; ++n)                                  \
          po[m][n] = MFMA_BF16(pa[m], vbr[n], po[m][n]);                                 \
      __builtin_amdgcn_s_setprio(0);                                                     \
    }                                                                                    \
  }

  LOAD_K(kfA, 0)
  STAGE_VT(0, 0)
  LOAD_K(kfB, 64)
  QKT(scA, kfA)

#define STEP(KN, KL, SCe, SCf, BUF, t)                                                   \
  {                                                                                      \
    QKT(SCf, KN)                                                                         \
    const int kt2 = ((t) + 2 < 32) ? ((t) + 2) * 64 : 0;                                 \
    LOAD_K(KL, kt2)                                                                      \
    EXPP(SCe)                                                                            \
    asm volatile("s_waitcnt vmcnt(8) lgkmcnt(0)" ::: "memory");                          \
    __builtin_amdgcn_s_barrier();                                                        \
    __builtin_amdgcn_sched_barrier(0);                                                   \
    const int ktn = ((t) + 1 < 32) ? ((t) + 1) * 64 : 0;                                 \
    STAGE_VT(BUF ^ 1, ktn)                                                               \
    __builtin_amdgcn_sched_barrier(0);                                                   \
    PV(BUF)                                                                              \
  }

  for (int t = 0; t < 30; t += 2) {
    STEP(kfB, kfA, scA, scB, 0, t)
    STEP(kfA, kfB, scB, scA, 1, t + 1)
  }
  STEP(kfB, kfA, scA, scB, 0, 30)
  EXPP(scB)
  asm volatile("s_waitcnt vmcnt(0) lgkmcnt(0)" ::: "memory");
  __builtin_amdgcn_s_barrier();
  __builtin_amdgcn_sched_barrier(0);
  PV(1)
#undef STEP
#undef PV
#undef EXPP
#undef QKT
#undef LOAD_K
#undef STAGE_VT

#pragma unroll
  for (int d = 1; d < 16; d <<= 1)
#pragma unroll
    for (int m = 0; m < 2; ++m)
#pragma unroll
      for (int r = 0; r < 4; ++r) lrun[m][r] += __shfl_xor(lrun[m][r], d);

  float linv[2][4];
#pragma unroll
  for (int m = 0; m < 2; ++m)
#pragma unroll
    for (int r = 0; r < 4; ++r) linv[m][r] = 1.0f / lrun[m][r];

  const int b = bh >> 4, hh = bh & 15;
#pragma unroll
  for (int m = 0; m < 2; ++m)
#pragma unroll
    for (int n = 0; n < 4; ++n)
#pragma unroll
      for (int r = 0; r < 4; ++r) {
        const int qrow = qw + m * 16 + lg * 4 + r;
        const int d = n * 16 + lr;
        o[((size_t)b * 2048 + qrow) * 1024 + hh * 64 + d] =
            f2bf(po[m][n][r] * linv[m][r]);
      }
}

// ---------------- launcher ----------------
extern "C" void kernel_launch(void* const* d_in, const int* in_sizes, int n_in,
                              void* d_out, int out_size, void* d_ws, size_t ws_size,
                              hipStream_t stream) {
  const float* x  = (const float*)d_in[0];
  const float* Wq = (const float*)d_in[1];
  const float* bq = (const float*)d_in[2];
  const float* Wk = (const float*)d_in[3];
  const float* bk = (const float*)d_in[4];
  const float* Wv = (const float*)d_in[5];
  const float* bv = (const float*)d_in[6];
  const float* Wo = (const float*)d_in[7];
  const float* bo = (const float*)d_in[8];
  const float* W1 = (const float*)d_in[9];
  const float* b1 = (const float*)d_in[10];
  const float* W2 = (const float*)d_in[11];
  const float* b2 = (const float*)d_in[12];
  const float* g1 = (const float*)d_in[13];
  const float* be1 = (const float*)d_in[14];
  const float* g2 = (const float*)d_in[15];
  const float* be2 = (const float*)d_in[16];

  char* ws = (char*)d_ws;
  const size_t MB = 1024 * 1024;
  unsigned short* Wqkv_b = (unsigned short*)(ws + 0 * MB);
  unsigned short* Wo_b   = (unsigned short*)(ws + 6 * MB);
  unsigned short* W1_b   = (unsigned short*)(ws + 8 * MB);
  unsigned short* W2_b   = (unsigned short*)(ws + 16 * MB);
  unsigned short* h_b    = (unsigned short*)(ws + 24 * MB);
  unsigned short* qb     = (unsigned short*)(ws + 32 * MB);  // q|k|v^T contiguous
  unsigned short* ab     = (unsigned short*)(ws + 56 * MB);
  unsigned short* x1b    = (unsigned short*)(ws + 64 * MB);  // bf16 residual (8 MB)
  unsigned short* fb     = (unsigned short*)(ws + 32 * MB);  // reuse q/k/v region
  unsigned short* p0     = (unsigned short*)(ws + 0 * MB);   // FFN2 partial 0 (8 MB)
  unsigned short* p1     = (unsigned short*)(ws + 8 * MB);   // FFN2 partial 1 (8 MB)

  // weight conversions + LN1 fused into one launch
  cvt_ln<<<16384, 256, 0, stream>>>(Wq, Wk, Wv, Wo, W1, W2, Wqkv_b, Wo_b, W1_b, W2_b,
                                    x, g1, be1, h_b);

  // fused QKV projection (EPI 0: q,k permuted; v transposed+sigma, coalesced)
  gemm_bf16<128, 0><<<768, 256, 0, stream>>>(h_b, Wqkv_b, bq, bk, bv, nullptr, qb,
                                             4096, 3072, 1024, 24, 32, 1024);

  // attention: x = head (XCD locality), y = q-block (QBLK=128)
  attn_kernel<<<dim3(32, 16), 256, 0, stream>>>(qb, qb + 4194304, qb + 2 * 4194304, ab);

  // O-proj + residual -> x1b (bf16)
  gemm_bf16<64, 2, 3><<<512, 256, 0, stream>>>(ab, Wo_b, bo, nullptr, nullptr, x, x1b,
                                               4096, 1024, 1024, 16, 32, 1024);

  // LN2 (bf16 input)
  ln_kernel_b<<<4096, 256, 0, stream>>>(x1b, g2, be2, h_b);

  // FFN1 (relu, bf16), 256^2 tiles, 8 waves
  gemm256<256, 256, 1><<<256, 512, 0, stream>>>(h_b, W1_b, b1, nullptr, fb,
                                                4096, 4096, 1024, 16, 16, 1024);

  // FFN2 split-K=2, bf16 raw partials (slice0 -> p0, slice1 -> p1)
  gemm256<128, 256, 4><<<256, 512, 0, stream>>>(fb, W2_b, nullptr, p1, p0,
                                                4096, 1024, 4096, 4, 32, 2048);

  // final reduce: d_out = p0 + p1 + x1b + b2
  ffn2_reduce<<<4096, 256, 0, stream>>>((float*)d_out, p0, p1, x1b, b2);
}

// Round 23
// 228.173 us; speedup vs baseline: 1.1224x; 1.0073x over previous
//
#include <hip/hip_runtime.h>

typedef __attribute__((ext_vector_type(8))) short short8;
typedef __attribute__((ext_vector_type(4))) float f32x4;
typedef __attribute__((ext_vector_type(4))) unsigned short us4;

#define MFMA_BF16(a, b, c) __builtin_amdgcn_mfma_f32_16x16x32_bf16((a), (b), (c), 0, 0, 0)

__device__ __forceinline__ unsigned short f2bf(float f) {
  union { float f; unsigned int u; } x; x.f = f;
  unsigned int r = x.u + 0x7FFFu + ((x.u >> 16) & 1u);
  return (unsigned short)(r >> 16);
}
__device__ __forceinline__ float bf2f(unsigned short b) {
  union { float f; unsigned int u; } x; x.u = ((unsigned int)b) << 16;
  return x.f;
}

typedef __attribute__((address_space(3))) unsigned int lds_uint;
typedef const __attribute__((address_space(1))) unsigned int gbl_uint;

__device__ __forceinline__ void gload_lds16(const void* g, void* l) {
  __builtin_amdgcn_global_load_lds((gbl_uint*)g, (lds_uint*)l, 16, 0, 0);
}

// swizzled LDS read: row stride 128 B, colbyte XOR'd with (row&7)<<4
__device__ __forceinline__ short8 lds_swz_read(const unsigned short* base, int row, int colbyte) {
  return *(const short8*)((const char*)base + row * 128 + (colbyte ^ ((row & 7) << 4)));
}

// ------ fused: weight fp32->bf16 convert (blocks 0..12287) + LN1 (12288..16383) --
__global__ __launch_bounds__(256) void cvt_ln(const float* __restrict__ Wq,
                                              const float* __restrict__ Wk,
                                              const float* __restrict__ Wv,
                                              const float* __restrict__ Wo,
                                              const float* __restrict__ W1,
                                              const float* __restrict__ W2,
                                              unsigned short* __restrict__ Wqkv_b,
                                              unsigned short* __restrict__ Wo_b,
                                              unsigned short* __restrict__ W1_b,
                                              unsigned short* __restrict__ W2_b,
                                              const float* __restrict__ x,
                                              const float* __restrict__ g,
                                              const float* __restrict__ be,
                                              unsigned short* __restrict__ lnout) {
  const int b = blockIdx.x;
  const int t = threadIdx.x;
  __shared__ float red[8];
  if (b < 12288) {
    const float* src;
    unsigned short* dst;
    int off;
    if (b < 1024)      { src = Wq; dst = Wqkv_b;           off = b; }
    else if (b < 2048) { src = Wk; dst = Wqkv_b + 1048576; off = b - 1024; }
    else if (b < 3072) { src = Wv; dst = Wqkv_b + 2097152; off = b - 2048; }
    else if (b < 4096) { src = Wo; dst = Wo_b;             off = b - 3072; }
    else if (b < 8192) { src = W1; dst = W1_b;             off = b - 4096; }
    else               { src = W2; dst = W2_b;             off = b - 8192; }
    const int i = off * 256 + t;
    const float4 v = ((const float4*)src)[i];
    us4 o;
    o.x = f2bf(v.x); o.y = f2bf(v.y); o.z = f2bf(v.z); o.w = f2bf(v.w);
    ((us4*)dst)[i] = o;
    return;
  }
  const int row = b - 12288;
  const float4 v = ((const float4*)(x + (size_t)row * 1024))[t];
  float s = v.x + v.y + v.z + v.w;
  float s2 = v.x * v.x + v.y * v.y + v.z * v.z + v.w * v.w;
#pragma unroll
  for (int d = 1; d < 64; d <<= 1) {
    s += __shfl_xor(s, d);
    s2 += __shfl_xor(s2, d);
  }
  const int wid = t >> 6, lane = t & 63;
  if (lane == 0) { red[wid] = s; red[4 + wid] = s2; }
  __syncthreads();
  s = red[0] + red[1] + red[2] + red[3];
  s2 = red[4] + red[5] + red[6] + red[7];
  const float mu = s * (1.0f / 1024.0f);
  const float var = s2 * (1.0f / 1024.0f) - mu * mu;
  const float rstd = rsqrtf(var + 1e-5f);
  const float4 gv = ((const float4*)g)[t];
  const float4 bv = ((const float4*)be)[t];
  us4 o;
  o.x = f2bf((v.x - mu) * rstd * gv.x + bv.x);
  o.y = f2bf((v.y - mu) * rstd * gv.y + bv.y);
  o.z = f2bf((v.z - mu) * rstd * gv.z + bv.z);
  o.w = f2bf((v.w - mu) * rstd * gv.w + bv.w);
  ((us4*)(lnout + (size_t)row * 1024))[t] = o;
}

// ---------------- layernorm, bf16 input: bf16 in -> bf16 out (1024 cols) --------
__global__ __launch_bounds__(256) void ln_kernel_b(const unsigned short* __restrict__ xb,
                                                   const float* __restrict__ g,
                                                   const float* __restrict__ be,
                                                   unsigned short* __restrict__ out) {
  const int row = blockIdx.x;
  const int t = threadIdx.x;
  const us4 v4 = *(const us4*)(xb + (size_t)row * 1024 + t * 4);
  float v0 = bf2f(v4.x), v1 = bf2f(v4.y), v2 = bf2f(v4.z), v3 = bf2f(v4.w);
  float s = v0 + v1 + v2 + v3;
  float s2 = v0 * v0 + v1 * v1 + v2 * v2 + v3 * v3;
#pragma unroll
  for (int d = 1; d < 64; d <<= 1) {
    s += __shfl_xor(s, d);
    s2 += __shfl_xor(s2, d);
  }
  __shared__ float red[8];
  const int wid = t >> 6, lane = t & 63;
  if (lane == 0) { red[wid] = s; red[4 + wid] = s2; }
  __syncthreads();
  s = red[0] + red[1] + red[2] + red[3];
  s2 = red[4] + red[5] + red[6] + red[7];
  const float mu = s * (1.0f / 1024.0f);
  const float var = s2 * (1.0f / 1024.0f) - mu * mu;
  const float rstd = rsqrtf(var + 1e-5f);
  const float4 gv = ((const float4*)g)[t];
  const float4 bv = ((const float4*)be)[t];
  us4 o;
  o.x = f2bf((v0 - mu) * rstd * gv.x + bv.x);
  o.y = f2bf((v1 - mu) * rstd * gv.y + bv.y);
  o.z = f2bf((v2 - mu) * rstd * gv.z + bv.z);
  o.w = f2bf((v3 - mu) * rstd * gv.w + bv.w);
  *(us4*)(out + (size_t)row * 1024 + t * 4) = o;
}

// ---------------- FFN2 reduce: out = bf16(p0)+bf16(p1) + bf16(x1) + b2 ----------
__global__ __launch_bounds__(256) void ffn2_reduce(float* __restrict__ out,
                                                   const unsigned short* __restrict__ p0,
                                                   const unsigned short* __restrict__ p1,
                                                   const unsigned short* __restrict__ x1b,
                                                   const float* __restrict__ b2) {
  const int row = blockIdx.x, t = threadIdx.x;
  const size_t i = (size_t)row * 256 + t;
  const us4 a0 = ((const us4*)p0)[i];
  const us4 a1 = ((const us4*)p1)[i];
  const us4 c = ((const us4*)x1b)[i];
  const float4 b = ((const float4*)b2)[t];
  float4 v;
  v.x = bf2f(a0.x) + bf2f(a1.x) + bf2f(c.x) + b.x;
  v.y = bf2f(a0.y) + bf2f(a1.y) + bf2f(c.y) + b.y;
  v.z = bf2f(a0.z) + bf2f(a1.z) + bf2f(c.z) + b.z;
  v.w = bf2f(a0.w) + bf2f(a1.w) + bf2f(c.w) + b.w;
  ((float4*)out)[i] = v;
}

// ---------------- GEMM (4-wave, 128-row tiles): counted-vmcnt + T2 swizzle ------
// EPI 0: fused-QKV store (q,k permuted; v transposed+sigma via LDS, coalesced).
// EPI 1: relu bf16; EPI 2: +res(fp32), store BF16.
template <int BN, int EPI, int MINW = 2>
__global__ __launch_bounds__(256, MINW) void gemm_bf16(const unsigned short* __restrict__ A,
                                                       const unsigned short* __restrict__ B,
                                                       const float* __restrict__ bias,
                                                       const float* __restrict__ biasK,
                                                       const float* __restrict__ biasV,
                                                       const float* __restrict__ res,
                                                       void* __restrict__ outp,
                                                       int M, int N, int K,
                                                       int gx, int gy, int kspl) {
  constexpr int WN = (BN == 128) ? 2 : 1;
  constexpr int WROWS = 128 / (4 / WN);
  constexpr int MW = WROWS / 16;
  constexpr int NW = (BN / WN) / 16;
  constexpr int BCH = BN / 32;
  constexpr int LOADS = 4 + BCH;

  __shared__ __align__(16) unsigned short SMEM[2 * 128 * 64 + 2 * BN * 64];
  auto As = (unsigned short(*)[128 * 64])SMEM;
  auto Bs = (unsigned short(*)[BN * 64])(SMEM + 2 * 128 * 64);

  const int nwg = gridDim.x;
  const int id2 = ((int)blockIdx.x & 7) * (nwg >> 3) + ((int)blockIdx.x >> 3);
  const int bx = id2 % gx;
  const int byz = id2 / gx;
  const int by = byz % gy;
  const int bz = byz / gy;

  const int wid = threadIdx.x >> 6;
  const int lane = threadIdx.x & 63;
  const int lr = lane & 15, lg = lane >> 4;
  const int row0 = by * 128;
  const int col0 = bx * BN;
  const int k0 = bz * kspl;
  const int wm = (wid / WN) * WROWS;
  const int wn = (wid % WN) * (BN / WN);

  const int scol = ((lane & 7) ^ ((lane >> 3) & 7)) * 8;

  auto stage = [&](int buf, int kt) {
#pragma unroll
    for (int i = 0; i < 4; ++i) {
      const int r = wid * 32 + i * 8;
      gload_lds16(A + (size_t)(row0 + r + (lane >> 3)) * K + kt + scol,
                  (void*)&As[buf][r * 64]);
    }
#pragma unroll
    for (int i = 0; i < BCH; ++i) {
      const int r = wid * (8 * BCH) + i * 8;
      gload_lds16(B + (size_t)(col0 + r + (lane >> 3)) * K + kt + scol,
                  (void*)&Bs[buf][r * 64]);
    }
  };

  f32x4 acc[MW][NW];
#pragma unroll
  for (int m = 0; m < MW; ++m)
#pragma unroll
    for (int n = 0; n < NW; ++n) acc[m][n] = (f32x4){0.f, 0.f, 0.f, 0.f};

  auto mma = [&](int buf) {
#pragma unroll
    for (int kk = 0; kk < 64; kk += 32) {
      const int colbyte = kk * 2 + lg * 16;
      short8 av[MW], bv[NW];
#pragma unroll
      for (int m = 0; m < MW; ++m)
        av[m] = lds_swz_read(&As[buf][0], wm + m * 16 + lr, colbyte);
#pragma unroll
      for (int n = 0; n < NW; ++n)
        bv[n] = lds_swz_read(&Bs[buf][0], wn + n * 16 + lr, colbyte);
#pragma unroll
      for (int m = 0; m < MW; ++m)
#pragma unroll
        for (int n = 0; n < NW; ++n) acc[m][n] = MFMA_BF16(av[m], bv[n], acc[m][n]);
    }
  };

  stage(0, k0);
  stage(1, k0 + 64);
  const int ktend = k0 + kspl;
  int cur = 0;
  for (int kt = k0; kt < ktend - 64; kt += 64) {
    asm volatile("s_waitcnt vmcnt(%0)" ::"i"(LOADS) : "memory");
    __builtin_amdgcn_s_barrier();
    __builtin_amdgcn_sched_barrier(0);
    mma(cur);
    __builtin_amdgcn_s_barrier();
    if (kt + 128 < ktend) stage(cur, kt + 128);
    cur ^= 1;
  }
  asm volatile("s_waitcnt vmcnt(0)" ::: "memory");
  __builtin_amdgcn_s_barrier();
  __builtin_amdgcn_sched_barrier(0);
  mma(cur);

  if constexpr (EPI == 0) {
    const int which = col0 >> 10;  // uniform per block (col0 multiple of 128)
    if (which < 2) {
#pragma unroll
      for (int m = 0; m < MW; ++m)
#pragma unroll
        for (int n = 0; n < NW; ++n)
#pragma unroll
          for (int r = 0; r < 4; ++r) {
            const int row = row0 + wm + m * 16 + lg * 4 + r;
            const int col = col0 + wn + n * 16 + lr;
            const int c = col & 1023;
            const float* bp = (which == 0) ? bias : biasK;
            const float v = acc[m][n][r] + bp[c];
            const size_t idx = (size_t)which * 4194304 +
                ((((size_t)(row >> 11)) * 16 + (c >> 6)) * 2048 + (row & 2047)) * 64 +
                (c & 63);
            ((unsigned short*)outp)[idx] = f2bf(v);
          }
    } else {
      // V tile: sigma-permuted transpose via reused LDS, then coalesced V^T store
      unsigned short* Vlds = SMEM;
      __syncthreads();
#pragma unroll
      for (int m = 0; m < MW; ++m)
#pragma unroll
        for (int n = 0; n < NW; ++n)
#pragma unroll
          for (int r = 0; r < 4; ++r) {
            const int rl = wm + m * 16 + lg * 4 + r;
            const int xx = rl & 63;
            const int rs = (rl & ~63) | ((xx & 15) << 2) | (xx >> 4);
            const int coll = wn + n * 16 + lr;
            const float v = acc[m][n][r] + biasV[(col0 & 1023) + coll];
            Vlds[coll * 144 + rs] = f2bf(v);
          }
      __syncthreads();
      const int cl = threadIdx.x >> 1, h = threadIdx.x & 1;
      const int c = (col0 & 1023) + cl;
      const int bb = row0 >> 11;
      unsigned short* vdst = (unsigned short*)outp + (size_t)2 * 4194304 +
          (((size_t)bb * 16 + (c >> 6)) * 64 + (c & 63)) * 2048 + (row0 & 2047) + h * 64;
#pragma unroll
      for (int w = 0; w < 8; ++w)
        *(short8*)(vdst + w * 8) = *(const short8*)&Vlds[cl * 144 + h * 64 + w * 8];
    }
  } else {
#pragma unroll
    for (int m = 0; m < MW; ++m) {
#pragma unroll
      for (int n = 0; n < NW; ++n) {
#pragma unroll
        for (int r = 0; r < 4; ++r) {
          const int row = row0 + wm + m * 16 + lg * 4 + r;
          const int col = col0 + wn + n * 16 + lr;
          if constexpr (EPI == 1) {
            const float v = acc[m][n][r] + bias[col];
            ((unsigned short*)outp)[(size_t)row * N + col] = f2bf(fmaxf(v, 0.f));
          } else {
            const float v = acc[m][n][r] + bias[col] + res[(size_t)row * N + col];
            ((unsigned short*)outp)[(size_t)row * N + col] = f2bf(v);
          }
        }
      }
    }
  }
}

// ---------------- GEMM (8-wave, BMxBN tiles): counted-vmcnt + T2 swizzle --------
// NBUF=2 (FFN1, 128KB LDS) or 3 (FFN2, 144KB LDS, 1 block/CU anyway): deeper
// pipeline gives each tile's loads ~2 iterations of flight time.
template <int BM, int BN, int EPI, int NBUF = 2>
__global__ __launch_bounds__(512, NBUF == 2 ? 2 : 1) void gemm256(
    const unsigned short* __restrict__ A,
    const unsigned short* __restrict__ B,
    const float* __restrict__ bias,
    void* __restrict__ part,
    void* __restrict__ outp,
    int M, int N, int K,
    int gx, int gy, int kspl) {
  constexpr int MW = BM / 32;
  constexpr int NW = BN / 64;
  constexpr int A_ISS = BM / 64;
  constexpr int B_ISS = BN / 64;
  constexpr int LOADS = A_ISS + B_ISS;

  __shared__ __align__(16) unsigned short As[NBUF][BM * 64];
  __shared__ __align__(16) unsigned short Bs[NBUF][BN * 64];

  const int nwg = gridDim.x;
  const int id2 = ((int)blockIdx.x & 7) * (nwg >> 3) + ((int)blockIdx.x >> 3);
  const int bx = id2 % gx;
  const int byz = id2 / gx;
  const int by = byz % gy;
  const int bz = byz / gy;

  const int wid = threadIdx.x >> 6;
  const int lane = threadIdx.x & 63;
  const int lr = lane & 15, lg = lane >> 4;
  const int wr = wid >> 2, wc = wid & 3;
  const int row0 = by * BM;
  const int col0 = bx * BN;
  const int k0 = bz * kspl;
  const int wm = wr * (BM / 2);
  const int wn = wc * (BN / 4);

  const int scol = ((lane & 7) ^ ((lane >> 3) & 7)) * 8;

  auto stage = [&](int buf, int kt) {
#pragma unroll
    for (int i = 0; i < A_ISS; ++i) {
      const int r = wid * 8 + i * 64;
      gload_lds16(A + (size_t)(row0 + r + (lane >> 3)) * K + kt + scol,
                  (void*)&As[buf][r * 64]);
    }
#pragma unroll
    for (int i = 0; i < B_ISS; ++i) {
      const int r = wid * 8 + i * 64;
      gload_lds16(B + (size_t)(col0 + r + (lane >> 3)) * K + kt + scol,
                  (void*)&Bs[buf][r * 64]);
    }
  };

  f32x4 acc[MW][NW];
#pragma unroll
  for (int m = 0; m < MW; ++m)
#pragma unroll
    for (int n = 0; n < NW; ++n) acc[m][n] = (f32x4){0.f, 0.f, 0.f, 0.f};

  auto mma = [&](int buf) {
#pragma unroll
    for (int kk = 0; kk < 64; kk += 32) {
      const int colbyte = kk * 2 + lg * 16;
      short8 av[MW], bv[NW];
#pragma unroll
      for (int m = 0; m < MW; ++m)
        av[m] = lds_swz_read(&As[buf][0], wm + m * 16 + lr, colbyte);
#pragma unroll
      for (int n = 0; n < NW; ++n)
        bv[n] = lds_swz_read(&Bs[buf][0], wn + n * 16 + lr, colbyte);
#pragma unroll
      for (int m = 0; m < MW; ++m)
#pragma unroll
        for (int n = 0; n < NW; ++n) acc[m][n] = MFMA_BF16(av[m], bv[n], acc[m][n]);
    }
  };

  const int nt = kspl / 64;  // K-tiles
  if constexpr (NBUF == 2) {
    stage(0, k0);
    stage(1, k0 + 64);
    int cur = 0;
    for (int t = 0; t < nt - 1; ++t) {
      asm volatile("s_waitcnt vmcnt(%0)" ::"i"(LOADS) : "memory");
      __builtin_amdgcn_s_barrier();
      __builtin_amdgcn_sched_barrier(0);
      mma(cur);
      __builtin_amdgcn_s_barrier();
      if (t + 2 < nt) stage(cur, k0 + (t + 2) * 64);
      cur ^= 1;
    }
    asm volatile("s_waitcnt vmcnt(0)" ::: "memory");
    __builtin_amdgcn_s_barrier();
    __builtin_amdgcn_sched_barrier(0);
    mma(cur);
  } else {
    // 3-deep: tiles t+1, t+2 in flight across each compute; vmcnt(2*LOADS)
    stage(0, k0);
    stage(1, k0 + 64);
    stage(2, k0 + 128);
    int cur = 0;
    for (int t = 0; t < nt - 2; ++t) {
      asm volatile("s_waitcnt vmcnt(%0)" ::"i"(2 * LOADS) : "memory");
      __builtin_amdgcn_s_barrier();
      __builtin_amdgcn_sched_barrier(0);
      mma(cur);
      __builtin_amdgcn_s_barrier();
      if (t + 3 < nt) stage(cur, k0 + (t + 3) * 64);
      cur = (cur == 2) ? 0 : cur + 1;
    }
    asm volatile("s_waitcnt vmcnt(%0)" ::"i"(LOADS) : "memory");
    __builtin_amdgcn_s_barrier();
    __builtin_amdgcn_sched_barrier(0);
    mma(cur);
    cur = (cur == 2) ? 0 : cur + 1;
    asm volatile("s_waitcnt vmcnt(0)" ::: "memory");
    __builtin_amdgcn_s_barrier();
    __builtin_amdgcn_sched_barrier(0);
    mma(cur);
  }

#pragma unroll
  for (int m = 0; m < MW; ++m) {
#pragma unroll
    for (int n = 0; n < NW; ++n) {
#pragma unroll
      for (int r = 0; r < 4; ++r) {
        const int row = row0 + wm + m * 16 + lg * 4 + r;
        const int col = col0 + wn + n * 16 + lr;
        if constexpr (EPI == 1) {
          const float v = acc[m][n][r] + bias[col];
          ((unsigned short*)outp)[(size_t)row * N + col] = f2bf(fmaxf(v, 0.f));
        } else {
          unsigned short* dst = (unsigned short*)(bz ? part : outp);
          dst[(size_t)row * N + col] = f2bf(acc[m][n][r]);
        }
      }
    }
  }
}

// ---------------- flash attention v5 (frozen R22 config) ------------------------
__global__ __launch_bounds__(256, 2) void attn_kernel(const unsigned short* __restrict__ q,
                                                      const unsigned short* __restrict__ k,
                                                      const unsigned short* __restrict__ vt,
                                                      unsigned short* __restrict__ o) {
  const int bh = blockIdx.x;
  const int q0 = blockIdx.y * 128;
  const unsigned short* qh = q + (size_t)bh * 2048 * 64;
  const unsigned short* kh = k + (size_t)bh * 2048 * 64;
  const unsigned short* vh = vt + (size_t)bh * 64 * 2048;  // [d][s]
  const int wid = threadIdx.x >> 6, lane = threadIdx.x & 63;
  const int lr = lane & 15, lg = lane >> 4;
  const int qw = q0 + wid * 32;

  __shared__ __align__(16) unsigned short Vt[2][64 * 64];
  __shared__ __align__(16) unsigned short Ps[4][32 * 64];

  constexpr float CS = 0.125f * 1.4426950408889634f;
  short8 qf[2][2];
#pragma unroll
  for (int m = 0; m < 2; ++m)
#pragma unroll
    for (int kk = 0; kk < 2; ++kk) {
      short8 t = *(const short8*)&qh[(size_t)(qw + m * 16 + lr) * 64 + kk * 32 + lg * 8];
#pragma unroll
      for (int j = 0; j < 8; ++j) t[j] = (short)f2bf(bf2f((unsigned short)t[j]) * CS);
      qf[m][kk] = t;
    }

  f32x4 po[2][4];
  float lrun[2][4];
#pragma unroll
  for (int m = 0; m < 2; ++m) {
#pragma unroll
    for (int n = 0; n < 4; ++n) po[m][n] = (f32x4){0.f, 0.f, 0.f, 0.f};
#pragma unroll
    for (int r = 0; r < 4; ++r) lrun[m][r] = 0.f;
  }

  const int scol = ((lane & 7) ^ ((lane >> 3) & 7)) * 8;
  char* const PsB = (char*)&Ps[wid][0];

  short8 kfA[4][2], kfB[4][2];
  f32x4 scA[2][4], scB[2][4];

#define LOAD_K(KF, kt)                                                                   \
  {                                                                                      \
    _Pragma("unroll") for (int n = 0; n < 4; ++n) _Pragma("unroll") for (int kk = 0;     \
                                                                         kk < 2; ++kk)  \
        KF[n][kk] =                                                                      \
        *(const short8*)&kh[(size_t)((kt) + n * 16 + lr) * 64 + kk * 32 + lg * 8];       \
  }
#define STAGE_VT(BUF, kt)                                                                \
  {                                                                                      \
    _Pragma("unroll") for (int i = 0; i < 2; ++i) {                                      \
      const int r = (wid * 2 + i) * 8;                                                   \
      gload_lds16(vh + (size_t)(r + (lane >> 3)) * 2048 + (kt) + scol,                   \
                  (void*)&Vt[BUF][r * 64]);                                              \
    }                                                                                    \
  }
#define QKT(SC, KF)                                                                      \
  {                                                                                      \
    _Pragma("unroll") for (int m = 0; m < 2; ++m) _Pragma("unroll") for (int n = 0;      \
                                                                         n < 4; ++n)    \
        SC[m][n] = (f32x4){0.f, 0.f, 0.f, 0.f};                                          \
    __builtin_amdgcn_s_setprio(1);                                                       \
    _Pragma("unroll") for (int kk = 0; kk < 2; ++kk)                                     \
        _Pragma("unroll") for (int m = 0; m < 2; ++m)                                    \
        _Pragma("unroll") for (int n = 0; n < 4; ++n)                                    \
        SC[m][n] = MFMA_BF16(qf[m][kk], KF[n][kk], SC[m][n]);                            \
    __builtin_amdgcn_s_setprio(0);                                                       \
  }
#define EXPP(SC)                                                                         \
  {                                                                                      \
    _Pragma("unroll") for (int m = 0; m < 2; ++m)                                        \
        _Pragma("unroll") for (int r = 0; r < 4; ++r) {                                  \
      const float p0 = __builtin_amdgcn_exp2f(SC[m][0][r]);                              \
      const float p1 = __builtin_amdgcn_exp2f(SC[m][1][r]);                              \
      const float p2 = __builtin_amdgcn_exp2f(SC[m][2][r]);                              \
      const float p3 = __builtin_amdgcn_exp2f(SC[m][3][r]);                              \
      lrun[m][r] += (p0 + p1) + (p2 + p3);                                               \
      unsigned int u0, u1;                                                               \
      asm("v_cvt_pk_bf16_f32 %0, %1, %2" : "=v"(u0) : "v"(p0), "v"(p1));                 \
      asm("v_cvt_pk_bf16_f32 %0, %1, %2" : "=v"(u1) : "v"(p2), "v"(p3));                 \
      const int row = m * 16 + lg * 4 + r;                                               \
      uint2 pk2; pk2.x = u0; pk2.y = u1;                                                 \
      *(uint2*)(PsB + row * 128 + ((lr * 8) ^ ((row & 7) << 4))) = pk2;                  \
    }                                                                                    \
  }
#define PV(BUF)                                                                          \
  {                                                                                      \
    _Pragma("unroll") for (int kk = 0; kk < 2; ++kk) {                                   \
      const int coff = kk * 64 + lg * 16;                                                \
      short8 pa[2], vbr[4];                                                              \
      _Pragma("unroll") for (int m = 0; m < 2; ++m) {                                    \
        const int prow = m * 16 + lr;                                                    \
        pa[m] = *(const short8*)(PsB + prow * 128 + (coff ^ ((prow & 7) << 4)));         \
      }                                                                                  \
      _Pragma("unroll") for (int n = 0; n < 4; ++n)                                      \
        vbr[n] = lds_swz_read(&Vt[BUF][0], n * 16 + lr, coff);                           \
      __builtin_amdgcn_s_setprio(1);                                                     \
      _Pragma("unroll") for (int m = 0; m < 2; ++m)                                      \
          _Pragma("unroll") for (int n = 0; n < 4; ++n)                                  \
          po[m][n] = MFMA_BF16(pa[m], vbr[n], po[m][n]);                                 \
      __builtin_amdgcn_s_setprio(0);                                                     \
    }                                                                                    \
  }

  LOAD_K(kfA, 0)
  STAGE_VT(0, 0)
  LOAD_K(kfB, 64)
  QKT(scA, kfA)

#define STEP(KN, KL, SCe, SCf, BUF, t)                                                   \
  {                                                                                      \
    QKT(SCf, KN)                                                                         \
    const int kt2 = ((t) + 2 < 32) ? ((t) + 2) * 64 : 0;                                 \
    LOAD_K(KL, kt2)                                                                      \
    EXPP(SCe)                                                                            \
    asm volatile("s_waitcnt vmcnt(8) lgkmcnt(0)" ::: "memory");                          \
    __builtin_amdgcn_s_barrier();                                                        \
    __builtin_amdgcn_sched_barrier(0);                                                   \
    const int ktn = ((t) + 1 < 32) ? ((t) + 1) * 64 : 0;                                 \
    STAGE_VT(BUF ^ 1, ktn)                                                               \
    __builtin_amdgcn_sched_barrier(0);                                                   \
    PV(BUF)                                                                              \
  }

  for (int t = 0; t < 30; t += 2) {
    STEP(kfB, kfA, scA, scB, 0, t)
    STEP(kfA, kfB, scB, scA, 1, t + 1)
  }
  STEP(kfB, kfA, scA, scB, 0, 30)
  EXPP(scB)
  asm volatile("s_waitcnt vmcnt(0) lgkmcnt(0)" ::: "memory");
  __builtin_amdgcn_s_barrier();
  __builtin_amdgcn_sched_barrier(0);
  PV(1)
#undef STEP
#undef PV
#undef EXPP
#undef QKT
#undef LOAD_K
#undef STAGE_VT

#pragma unroll
  for (int d = 1; d < 16; d <<= 1)
#pragma unroll
    for (int m = 0; m < 2; ++m)
#pragma unroll
      for (int r = 0; r < 4; ++r) lrun[m][r] += __shfl_xor(lrun[m][r], d);

  float linv[2][4];
#pragma unroll
  for (int m = 0; m < 2; ++m)
#pragma unroll
    for (int r = 0; r < 4; ++r) linv[m][r] = 1.0f / lrun[m][r];

  const int b = bh >> 4, hh = bh & 15;
#pragma unroll
  for (int m = 0; m < 2; ++m)
#pragma unroll
    for (int n = 0; n < 4; ++n)
#pragma unroll
      for (int r = 0; r < 4; ++r) {
        const int qrow = qw + m * 16 + lg * 4 + r;
        const int d = n * 16 + lr;
        o[((size_t)b * 2048 + qrow) * 1024 + hh * 64 + d] =
            f2bf(po[m][n][r] * linv[m][r]);
      }
}

// ---------------- launcher ----------------
extern "C" void kernel_launch(void* const* d_in, const int* in_sizes, int n_in,
                              void* d_out, int out_size, void* d_ws, size_t ws_size,
                              hipStream_t stream) {
  const float* x  = (const float*)d_in[0];
  const float* Wq = (const float*)d_in[1];
  const float* bq = (const float*)d_in[2];
  const float* Wk = (const float*)d_in[3];
  const float* bk = (const float*)d_in[4];
  const float* Wv = (const float*)d_in[5];
  const float* bv = (const float*)d_in[6];
  const float* Wo = (const float*)d_in[7];
  const float* bo = (const float*)d_in[8];
  const float* W1 = (const float*)d_in[9];
  const float* b1 = (const float*)d_in[10];
  const float* W2 = (const float*)d_in[11];
  const float* b2 = (const float*)d_in[12];
  const float* g1 = (const float*)d_in[13];
  const float* be1 = (const float*)d_in[14];
  const float* g2 = (const float*)d_in[15];
  const float* be2 = (const float*)d_in[16];

  char* ws = (char*)d_ws;
  const size_t MB = 1024 * 1024;
  unsigned short* Wqkv_b = (unsigned short*)(ws + 0 * MB);
  unsigned short* Wo_b   = (unsigned short*)(ws + 6 * MB);
  unsigned short* W1_b   = (unsigned short*)(ws + 8 * MB);
  unsigned short* W2_b   = (unsigned short*)(ws + 16 * MB);
  unsigned short* h_b    = (unsigned short*)(ws + 24 * MB);
  unsigned short* qb     = (unsigned short*)(ws + 32 * MB);  // q|k|v^T contiguous
  unsigned short* ab     = (unsigned short*)(ws + 56 * MB);
  unsigned short* x1b    = (unsigned short*)(ws + 64 * MB);  // bf16 residual (8 MB)
  unsigned short* fb     = (unsigned short*)(ws + 32 * MB);  // reuse q/k/v region
  unsigned short* p0     = (unsigned short*)(ws + 0 * MB);   // FFN2 partial 0 (8 MB)
  unsigned short* p1     = (unsigned short*)(ws + 8 * MB);   // FFN2 partial 1 (8 MB)

  // weight conversions + LN1 fused into one launch
  cvt_ln<<<16384, 256, 0, stream>>>(Wq, Wk, Wv, Wo, W1, W2, Wqkv_b, Wo_b, W1_b, W2_b,
                                    x, g1, be1, h_b);

  // fused QKV projection (EPI 0: q,k permuted; v transposed+sigma, coalesced)
  gemm_bf16<128, 0><<<768, 256, 0, stream>>>(h_b, Wqkv_b, bq, bk, bv, nullptr, qb,
                                             4096, 3072, 1024, 24, 32, 1024);

  // attention: x = head (XCD locality), y = q-block (QBLK=128)
  attn_kernel<<<dim3(32, 16), 256, 0, stream>>>(qb, qb + 4194304, qb + 2 * 4194304, ab);

  // O-proj + residual -> x1b (bf16)
  gemm_bf16<64, 2, 3><<<512, 256, 0, stream>>>(ab, Wo_b, bo, nullptr, nullptr, x, x1b,
                                               4096, 1024, 1024, 16, 32, 1024);

  // LN2 (bf16 input)
  ln_kernel_b<<<4096, 256, 0, stream>>>(x1b, g2, be2, h_b);

  // FFN1 (relu, bf16), 256^2 tiles, 8 waves, 2-buffer
  gemm256<256, 256, 1, 2><<<256, 512, 0, stream>>>(h_b, W1_b, b1, nullptr, fb,
                                                   4096, 4096, 1024, 16, 16, 1024);

  // FFN2 split-K=2, bf16 raw partials, 3-buffer deep pipeline
  gemm256<128, 256, 4, 3><<<256, 512, 0, stream>>>(fb, W2_b, nullptr, p1, p0,
                                                   4096, 1024, 4096, 4, 32, 2048);

  // final reduce: d_out = p0 + p1 + x1b + b2
  ffn2_reduce<<<4096, 256, 0, stream>>>((float*)d_out, p0, p1, x1b, b2);
}